// Round 2
// baseline (247.922 us; speedup 1.0000x reference)
//
#include <hip/hip_runtime.h>
#include <math.h>

// densityPropGRUCell on MI355X (gfx950).  B=128, U=D=256.
// R2: (a) GEMV-per-batch (192MB L2 re-reads, was 60us) -> tiled f32 GEMMs that
//     read U/W once; (b) WT fragment "packs" so MFMA B/A-operand loads are
//     fully coalesced 1KB wave-loads; (c) bf16 epilogue side-tensors
//     (Sigma_z stored bf16, S read as Sbf) to cut ~50MB of traffic.

typedef __attribute__((ext_vector_type(8))) short sh8;           // 8 x bf16 fragment
typedef __attribute__((ext_vector_type(4))) float f4;            // MFMA acc
typedef __attribute__((ext_vector_type(4))) unsigned short us4;  // 4 x bf16

__device__ __forceinline__ unsigned short f2bf(float f) {
  unsigned int u = __float_as_uint(f);
  u = (u + 0x7fffu + ((u >> 16) & 1u)) >> 16;  // RNE
  return (unsigned short)u;
}
__device__ __forceinline__ float bf2f(unsigned short u) {
  return __uint_as_float(((unsigned int)u) << 16);
}
__device__ __forceinline__ f4 mfma16(sh8 a, sh8 b, f4 c) {
  return __builtin_amdgcn_mfma_f32_16x16x32_bf16(a, b, c, 0, 0, 0);
}

// ---------------------------------------------------------------------------
// prepA: blocks [0,2048): S f32 -> bf16.  [2048,2176): per-batch reductions
// (sx, sp, trS).  block 2176: softplus(h) vectors.
// ---------------------------------------------------------------------------
__global__ __launch_bounds__(256) void prepA_kernel(
    const float* __restrict__ xin, const float* __restrict__ prev,
    const float* __restrict__ S,
    const float* __restrict__ whs, const float* __restrict__ uhs,
    unsigned short* __restrict__ Sbf,
    float* __restrict__ sxA, float* __restrict__ spA, float* __restrict__ trSA,
    float* __restrict__ sphw, float* __restrict__ sphu)
{
  const int blk = blockIdx.x, t = threadIdx.x;

  if (blk < 2048) {  // ---- S -> bf16 ----
    const f4* S4 = (const f4*)S;
    us4* O4 = (us4*)Sbf;
    const int base = blk * 256 + t;
#pragma unroll
    for (int i = 0; i < 4; ++i) {
      int idx = base + i * 524288;
      f4 v = S4[idx];
      us4 o;
      o[0] = f2bf(v[0]); o[1] = f2bf(v[1]); o[2] = f2bf(v[2]); o[3] = f2bf(v[3]);
      O4[idx] = o;
    }
    return;
  }

  if (blk < 2176) {  // ---- per-batch reductions ----
    const int b = blk - 2048;
    __shared__ float red[12];
    float x = xin[b * 256 + t];
    float p = prev[b * 256 + t];
    float d = S[(size_t)b * 65536 + (size_t)t * 257];
    float a0 = x * x, a1 = p * p, a2 = d;
#pragma unroll
    for (int off = 32; off; off >>= 1) {
      a0 += __shfl_down(a0, off, 64);
      a1 += __shfl_down(a1, off, 64);
      a2 += __shfl_down(a2, off, 64);
    }
    if ((t & 63) == 0) {
      int w = t >> 6;
      red[w] = a0; red[4 + w] = a1; red[8 + w] = a2;
    }
    __syncthreads();
    if (t == 0) {
      sxA[b] = red[0] + red[1] + red[2] + red[3];
      spA[b] = red[4] + red[5] + red[6] + red[7];
      trSA[b] = red[8] + red[9] + red[10] + red[11];
    }
    return;
  }

  // ---- softplus vectors for gate h ----
  sphw[t] = log1pf(expf(whs[t]));
  sphu[t] = log1pf(expf(uhs[t]));
}

// ---------------------------------------------------------------------------
// mzr: blocks [0,64): f32 GEMM  m_g = [x|p] @ [U_g;W_g]  (g = blk>>5, 8 cols
// per block) + sigmoid/diag epilogue.  Blocks [64,112): build WT fragment
// packs for all 3 gates (coalesced MFMA operand loads in the gate kernels).
// ---------------------------------------------------------------------------
__global__ __launch_bounds__(256) void mzr_kernel(
    const float* __restrict__ xin, const float* __restrict__ prev,
    const float* __restrict__ Uz, const float* __restrict__ Wz,
    const float* __restrict__ uzs, const float* __restrict__ wzs,
    const float* __restrict__ Ur, const float* __restrict__ Wr,
    const float* __restrict__ urs, const float* __restrict__ wrs,
    const float* __restrict__ Wh,
    const float* __restrict__ sxA, const float* __restrict__ spA,
    const float* __restrict__ trSA,
    float* __restrict__ zv, float* __restrict__ rv,
    float* __restrict__ gzv, float* __restrict__ grv,
    float* __restrict__ diagz, float* __restrict__ diagr,
    unsigned short* __restrict__ packs)
{
  const int blk = blockIdx.x, t = threadIdx.x;

  if (blk < 64) {
    const int g = blk >> 5, nb = blk & 31, c0 = nb * 8;
    const float* U = g ? Ur : Uz;
    const float* W = g ? Wr : Wz;
    __shared__ __align__(16) float xpb[128][65];
    __shared__ __align__(16) float wb[64][8];
    const int b = t & 127, ch = t >> 7;
    float acc[4] = {0.f, 0.f, 0.f, 0.f};

    for (int kc = 0; kc < 8; ++kc) {
      const int k0 = kc * 64;
#pragma unroll
      for (int i = 0; i < 32; ++i) {
        int e = t + i * 256;
        int row = e >> 6, col = e & 63;
        xpb[row][col] = (k0 < 256) ? xin[row * 256 + k0 + col]
                                   : prev[row * 256 + (k0 - 256) + col];
      }
#pragma unroll
      for (int i = 0; i < 2; ++i) {
        int e = t + i * 256;
        int r = e >> 3, c = e & 7;
        wb[r][c] = (k0 < 256) ? U[(k0 + r) * 256 + c0 + c]
                              : W[(k0 - 256 + r) * 256 + c0 + c];
      }
      __syncthreads();
#pragma unroll 8
      for (int k = 0; k < 64; ++k) {
        float xv = xpb[b][k];
        f4 wv = *reinterpret_cast<const f4*>(&wb[k][ch * 4]);
        acc[0] = fmaf(xv, wv[0], acc[0]);
        acc[1] = fmaf(xv, wv[1], acc[1]);
        acc[2] = fmaf(xv, wv[2], acc[2]);
        acc[3] = fmaf(xv, wv[3], acc[3]);
      }
      __syncthreads();
    }

    const float sd = spA[b] + trSA[b], sx = sxA[b];
    const float* us = g ? urs : uzs;
    const float* ws = g ? wrs : wzs;
#pragma unroll
    for (int j = 0; j < 4; ++j) {
      int c = c0 + ch * 4 + j;
      int idx = b * 256 + c;
      float zz = 1.f / (1.f + expf(-acc[j]));
      float dg = sd * log1pf(expf(ws[c])) + sx * log1pf(expf(us[c]));
      if (g == 0) { zv[idx] = zz; gzv[idx] = zz * (1.f - zz); diagz[idx] = dg; }
      else        { rv[idx] = zz; grv[idx] = zz * (1.f - zz); diagr[idx] = dg; }
    }
    return;
  }

  // ---- pack builder ----
  // pack p (0..5): gate = p>>1, which = p&1.  Each pack = 8192 chunks x 16B.
  // pack1 chunk c = nb<<11 | kt<<8 | ct<<6 | lane :
  //    n = nb*64+ct*16+(lane&15), k8 = kt*32+(lane>>4)*8
  // pack2 chunk c = wv<<11 | rt<<9 | jt<<6 | lane :
  //    n = wv*64+rt*16+(lane&15), k8 = jt*32+(lane>>4)*8
  // entry = bf16(W[k8+e][n]), e=0..7.
  const float* Ws0 = Wz; const float* Ws1 = Wr; const float* Ws2 = Wh;
  int gid = (blk - 64) * 256 + t;
#pragma unroll
  for (int q = 0; q < 4; ++q) {
    int cid = gid * 4 + q;          // 0..49151
    int p = cid >> 13, c = cid & 8191;
    const float* W = (p >> 1) == 0 ? Ws0 : ((p >> 1) == 1 ? Ws1 : Ws2);
    int lane = c & 63, l15 = lane & 15, lhi = lane >> 4;
    int n, k8;
    if ((p & 1) == 0) {
      int nb = (c >> 11) & 3, kt = (c >> 8) & 7, ct = (c >> 6) & 3;
      n = nb * 64 + ct * 16 + l15; k8 = kt * 32 + lhi * 8;
    } else {
      int wv = (c >> 11) & 3, rt = (c >> 9) & 3, jt = (c >> 6) & 7;
      n = wv * 64 + rt * 16 + l15; k8 = jt * 32 + lhi * 8;
    }
    union { unsigned short u[8]; uint4 v; } pk;
#pragma unroll
    for (int e = 0; e < 8; ++e) pk.u[e] = f2bf(W[(k8 + e) * 256 + n]);
    *reinterpret_cast<uint4*>(packs + (size_t)p * 65536 + (size_t)c * 8) = pk.v;
  }
}

// ---------------------------------------------------------------------------
// mh: blocks [0,32): f32 GEMM  m_h = [x|p*r] @ [U_h;W_h] + tanh epilogue
// (gh, p-h, mu).  Block 32: ssr reduction.
// ---------------------------------------------------------------------------
__global__ __launch_bounds__(256) void mh_kernel(
    const float* __restrict__ xin, const float* __restrict__ prev,
    const float* __restrict__ Uh, const float* __restrict__ Wh,
    const float* __restrict__ zv, const float* __restrict__ rv,
    float* __restrict__ ghv, float* __restrict__ pmhv,
    float* __restrict__ ssrA, float* __restrict__ muOut)
{
  const int blk = blockIdx.x, t = threadIdx.x;

  if (blk < 32) {
    const int c0 = blk * 8;
    __shared__ __align__(16) float xpb[128][65];
    __shared__ __align__(16) float wb[64][8];
    const int b = t & 127, ch = t >> 7;
    float acc[4] = {0.f, 0.f, 0.f, 0.f};

    for (int kc = 0; kc < 8; ++kc) {
      const int k0 = kc * 64;
#pragma unroll
      for (int i = 0; i < 32; ++i) {
        int e = t + i * 256;
        int row = e >> 6, col = e & 63;
        float v;
        if (k0 < 256) v = xin[row * 256 + k0 + col];
        else {
          int jj = row * 256 + (k0 - 256) + col;
          v = prev[jj] * rv[jj];
        }
        xpb[row][col] = v;
      }
#pragma unroll
      for (int i = 0; i < 2; ++i) {
        int e = t + i * 256;
        int r = e >> 3, c = e & 7;
        wb[r][c] = (k0 < 256) ? Uh[(k0 + r) * 256 + c0 + c]
                              : Wh[(k0 - 256 + r) * 256 + c0 + c];
      }
      __syncthreads();
#pragma unroll 8
      for (int k = 0; k < 64; ++k) {
        float xv = xpb[b][k];
        f4 wv = *reinterpret_cast<const f4*>(&wb[k][ch * 4]);
        acc[0] = fmaf(xv, wv[0], acc[0]);
        acc[1] = fmaf(xv, wv[1], acc[1]);
        acc[2] = fmaf(xv, wv[2], acc[2]);
        acc[3] = fmaf(xv, wv[3], acc[3]);
      }
      __syncthreads();
    }

#pragma unroll
    for (int j = 0; j < 4; ++j) {
      int c = c0 + ch * 4 + j;
      int idx = b * 256 + c;
      float h = tanhf(acc[j]);
      float p = prev[idx], z = zv[idx];
      ghv[idx] = 1.f - h * h;
      pmhv[idx] = p - h;
      muOut[idx] = z * p + (1.f - z) * h;
    }
    return;
  }

  // ---- ssr reduction: Sigma(sr^2) per batch ----
  const int b = t >> 1, half = t & 1;
  float s = 0.f;
  const int base = b * 256 + half * 128;
#pragma unroll 8
  for (int i = 0; i < 128; ++i) {
    float sr = prev[base + i] * rv[base + i];
    s = fmaf(sr, sr, s);
  }
  float tot = s + __shfl_down(s, 1, 64);
  if (half == 0) ssrA[b] = tot;
}

// ---------------------------------------------------------------------------
// Fused Y = W^T (A W) per (batch, 64-col block) with gate-specific epilogue.
// B-frags (stage1) and A-frags (stage2) come from coalesced packs.
// GATE 0 (z): bOut = Sigma_z  (bf16 ws)
// GATE 1 (r): bOut = sigma_g  (bf16 ws), trsgOut[b*4+nb] partial trace
// GATE 2 (h): fOut = Sigma_out (f32 d_out)
// ---------------------------------------------------------------------------
template <int GATE>
__global__ __launch_bounds__(256) void gate_kernel(
    const unsigned short* __restrict__ Amat,
    const unsigned short* __restrict__ pack1,
    const unsigned short* __restrict__ pack2,
    const unsigned short* __restrict__ Sb,    // Sbf (gates 1,2)
    const unsigned short* __restrict__ Szb,   // Szbf (gate 2)
    const float* __restrict__ v1, const float* __restrict__ dvec,
    const float* __restrict__ v2, const float* __restrict__ v3,
    const float* __restrict__ sxA, const float* __restrict__ ssrA,
    const float* __restrict__ trsgIn,
    const float* __restrict__ sphw, const float* __restrict__ sphu,
    float* __restrict__ fOut, unsigned short* __restrict__ bOut,
    float* __restrict__ trsgOut)
{
  __shared__ unsigned short Tt[64][264];  // T^T, padded row stride 528B
  __shared__ float ev0[256], ev1[256], ev2[256], ev3[256];

  const int b = blockIdx.x >> 2, nb = blockIdx.x & 3;
  const int tid = threadIdx.x;
  const int wave = tid >> 6, lane = tid & 63, lhi = lane >> 4, l15 = lane & 15;
  const size_t bb = (size_t)b << 16;

  {  // epilogue vectors
    const int u = tid;
    ev0[u] = v1[b * 256 + u];
    if constexpr (GATE == 0) { ev1[u] = dvec[b * 256 + u]; }
    if constexpr (GATE == 1) {
      ev1[u] = dvec[b * 256 + u];
      ev2[u] = v2[b * 256 + u];
      ev3[u] = v3[b * 256 + u];
    }
    if constexpr (GATE == 2) {
      float trsg = trsgIn[b * 4] + trsgIn[b * 4 + 1] + trsgIn[b * 4 + 2] + trsgIn[b * 4 + 3];
      ev1[u] = (ssrA[b] + trsg) * sphw[u] + sxA[b] * sphu[u];
      ev2[u] = v2[b * 256 + u];
      ev3[u] = v3[b * 256 + u];
    }
  }

  f4 acc[4][4];
  const f4 zero4 = {0.f, 0.f, 0.f, 0.f};
#pragma unroll
  for (int i = 0; i < 4; ++i)
#pragma unroll
    for (int j = 0; j < 4; ++j) acc[i][j] = zero4;

  // ---------------- stage 1: T = A_b @ W[:,col0:+64) ----------------
  const unsigned short* Ab = Amat + bb;
  const int kb = lhi * 8;
#pragma unroll
  for (int kt = 0; kt < 8; ++kt) {
    const int k = kt * 32 + kb;
    sh8 af[4], bfr[4];
#pragma unroll
    for (int rt = 0; rt < 4; ++rt)
      af[rt] = *reinterpret_cast<const sh8*>(Ab + ((wave * 64 + rt * 16 + l15) << 8) + k);
#pragma unroll
    for (int ct = 0; ct < 4; ++ct)
      bfr[ct] = *reinterpret_cast<const sh8*>(
          pack1 + ((size_t)((((nb * 8 + kt) * 4 + ct) * 64 + lane)) << 3));
#pragma unroll
    for (int rt = 0; rt < 4; ++rt)
#pragma unroll
      for (int ct = 0; ct < 4; ++ct)
        acc[rt][ct] = mfma16(af[rt], bfr[ct], acc[rt][ct]);
  }

  // write T^T (bf16) to LDS
#pragma unroll
  for (int rt = 0; rt < 4; ++rt) {
    const int row0 = wave * 64 + rt * 16 + lhi * 4;
#pragma unroll
    for (int ct = 0; ct < 4; ++ct) {
      const int c = ct * 16 + l15;
      us4 p;
      p[0] = f2bf(acc[rt][ct][0]); p[1] = f2bf(acc[rt][ct][1]);
      p[2] = f2bf(acc[rt][ct][2]); p[3] = f2bf(acc[rt][ct][3]);
      *reinterpret_cast<us4*>(&Tt[c][row0]) = p;
    }
  }
  __syncthreads();

#pragma unroll
  for (int i = 0; i < 4; ++i)
#pragma unroll
    for (int j = 0; j < 4; ++j) acc[i][j] = zero4;

  // ---------------- stage 2: Y = W^T @ T ----------------
#pragma unroll
  for (int jt = 0; jt < 8; ++jt) {
    const int j = jt * 32 + kb;
    sh8 af[4], bfr[4];
#pragma unroll
    for (int rt = 0; rt < 4; ++rt)
      af[rt] = *reinterpret_cast<const sh8*>(
          pack2 + ((size_t)((((wave * 4 + rt) * 8 + jt) * 64 + lane)) << 3));
#pragma unroll
    for (int ct = 0; ct < 4; ++ct)
      bfr[ct] = *reinterpret_cast<const sh8*>(&Tt[ct * 16 + l15][j]);
#pragma unroll
    for (int rt = 0; rt < 4; ++rt)
#pragma unroll
      for (int ct = 0; ct < 4; ++ct)
        acc[rt][ct] = mfma16(af[rt], bfr[ct], acc[rt][ct]);
  }

  // ---------------- epilogue ----------------
  const int col0 = nb * 64;
  float trloc = 0.f;
#pragma unroll
  for (int rt = 0; rt < 4; ++rt) {
    const int i0 = wave * 64 + rt * 16 + lhi * 4;
#pragma unroll
    for (int ct = 0; ct < 4; ++ct) {
      const int j = col0 + ct * 16 + l15;
#pragma unroll
      for (int rr = 0; rr < 4; ++rr) {
        const int i = i0 + rr;
        const float y = acc[rt][ct][rr];
        const size_t idx = bb + ((size_t)i << 8) + j;
        if constexpr (GATE == 0) {
          float yv = y + ((i == j) ? ev1[i] : 0.f);
          bOut[idx] = f2bf(yv * ev0[i] * ev0[j]);
        } else if constexpr (GATE == 1) {
          float Sr = (y + ((i == j) ? ev1[i] : 0.f)) * ev0[i] * ev0[j];
          float Sv = bf2f(Sb[idx]);
          float sg = Sr * (Sv + ev2[i] * ev2[j]) + ev3[i] * ev3[j] * Sv;
          bOut[idx] = f2bf(sg);
          if (i == j) trloc += sg;
        } else {
          float Sh = (y + ((i == j) ? ev1[i] : 0.f)) * ev0[i] * ev0[j];
          float Sv = bf2f(Sb[idx]);
          float Szv = bf2f(Szb[idx]);
          fOut[idx] = Szv * (Sv + Sh + ev3[i] * ev3[j])
                    + Sv * ev2[i] * ev2[j]
                    + Sh * (1.f - ev2[i]) * (1.f - ev2[j]);
        }
      }
    }
  }

  if constexpr (GATE == 1) {
    if (wave == nb) {
#pragma unroll
      for (int off = 32; off; off >>= 1) trloc += __shfl_down(trloc, off, 64);
      if (lane == 0) trsgOut[b * 4 + nb] = trloc;
    }
  }
}

// ---------------------------------------------------------------------------
extern "C" void kernel_launch(void* const* d_in, const int* in_sizes, int n_in,
                              void* d_out, int out_size, void* d_ws, size_t ws_size,
                              hipStream_t stream)
{
  const float* xin  = (const float*)d_in[0];
  const float* prev = (const float*)d_in[1];
  const float* S    = (const float*)d_in[2];
  const float* Uz = (const float*)d_in[3];  const float* uzs = (const float*)d_in[4];
  const float* Wz = (const float*)d_in[5];  const float* wzs = (const float*)d_in[6];
  const float* Ur = (const float*)d_in[7];  const float* urs = (const float*)d_in[8];
  const float* Wr = (const float*)d_in[9];  const float* wrs = (const float*)d_in[10];
  const float* Uh = (const float*)d_in[11]; const float* uhs = (const float*)d_in[12];
  const float* Wh = (const float*)d_in[13]; const float* whs = (const float*)d_in[14];

  float* muOut  = (float*)d_out;
  float* SigOut = muOut + 128 * 256;

  char* p = (char*)d_ws;
  auto take = [&](size_t bytes) { void* q = (void*)p; p += bytes; return q; };
  unsigned short* Sbf  = (unsigned short*)take(16777216);  // S bf16
  unsigned short* sg   = (unsigned short*)take(16777216);  // sigma_g bf16
  unsigned short* Szbf = (unsigned short*)take(16777216);  // Sigma_z bf16
  unsigned short* packs = (unsigned short*)take(786432);   // 6 x 128KB
  float* gzv   = (float*)take(131072);
  float* grv   = (float*)take(131072);
  float* ghv   = (float*)take(131072);
  float* zv    = (float*)take(131072);
  float* rv    = (float*)take(131072);
  float* pmhv  = (float*)take(131072);
  float* diagz = (float*)take(131072);
  float* diagr = (float*)take(131072);
  float* sphw  = (float*)take(1024);
  float* sphu  = (float*)take(1024);
  float* sxA   = (float*)take(512);
  float* spA   = (float*)take(512);
  float* trSA  = (float*)take(512);
  float* ssrA  = (float*)take(512);
  float* trsgP = (float*)take(2048);
  (void)in_sizes; (void)n_in; (void)out_size; (void)ws_size;

  unsigned short* p1z = packs;             // gate z pack1
  unsigned short* p2z = packs + 65536;     // gate z pack2
  unsigned short* p1r = packs + 2 * 65536;
  unsigned short* p2r = packs + 3 * 65536;
  unsigned short* p1h = packs + 4 * 65536;
  unsigned short* p2h = packs + 5 * 65536;

  prepA_kernel<<<2177, 256, 0, stream>>>(
      xin, prev, S, whs, uhs, Sbf, sxA, spA, trSA, sphw, sphu);

  mzr_kernel<<<112, 256, 0, stream>>>(
      xin, prev, Uz, Wz, uzs, wzs, Ur, Wr, urs, wrs, Wh,
      sxA, spA, trSA, zv, rv, gzv, grv, diagz, diagr, packs);

  mh_kernel<<<33, 256, 0, stream>>>(
      xin, prev, Uh, Wh, zv, rv, ghv, pmhv, ssrA, muOut);

  gate_kernel<0><<<512, 256, 0, stream>>>(
      Sbf, p1z, p2z, nullptr, nullptr, gzv, diagz, nullptr, nullptr,
      sxA, ssrA, nullptr, sphw, sphu, nullptr, Szbf, nullptr);

  gate_kernel<1><<<512, 256, 0, stream>>>(
      Sbf, p1r, p2r, Sbf, nullptr, grv, diagr, prev, rv,
      sxA, ssrA, nullptr, sphw, sphu, nullptr, sg, trsgP);

  gate_kernel<2><<<512, 256, 0, stream>>>(
      sg, p1h, p2h, Sbf, Szbf, ghv, nullptr, zv, pmhv,
      sxA, ssrA, trsgP, sphw, sphu, SigOut, nullptr, nullptr);
}

// Round 5
// 150.320 us; speedup vs baseline: 1.6493x; 1.6493x over previous
//
#include <hip/hip_runtime.h>
#include <math.h>

// densityPropGRUCell on MI355X (gfx950).  B=128, U=D=256.
// R5: proven-pieces-only rebuild.  R3/R4 failed (absmax nan / 11.0) with the
// MFMA mean path + cvt2 packing; R1/R2 passed.  This round:
//   prep : S->bf16 (R1) + WT bf16 (software RNE) + softplus vectors
//   mean : R1's f32 gate math, k-tiled with LDS-staged weights (fixes R1's
//          latency-bound 55us without touching numerics)
//   gate0/1/2 : R1's exact tiling, R2's bf16 side-tensors, software f2bf.

typedef __attribute__((ext_vector_type(8))) short sh8;           // 8 x bf16
typedef __attribute__((ext_vector_type(4))) float f4;
typedef __attribute__((ext_vector_type(4))) unsigned short us4;  // 4 x bf16

__device__ __forceinline__ unsigned short f2bf(float f) {  // software RNE
  unsigned int u = __float_as_uint(f);
  u = (u + 0x7fffu + ((u >> 16) & 1u)) >> 16;
  return (unsigned short)u;
}
__device__ __forceinline__ float bf2f(unsigned short u) {
  return __uint_as_float(((unsigned int)u) << 16);
}
__device__ __forceinline__ f4 mfma16(sh8 a, sh8 b, f4 c) {
  return __builtin_amdgcn_mfma_f32_16x16x32_bf16(a, b, c, 0, 0, 0);
}

// ---------------------------------------------------------------------------
// prep: [0,2048) S->bf16 (R1 verbatim); [2048,2144) WT_g[n][k]=bf16(W_g[k][n]);
// 2144: softplus(h) vectors.
// ---------------------------------------------------------------------------
__global__ __launch_bounds__(256) void prep_kernel(
    const float* __restrict__ S,
    const float* __restrict__ Wz, const float* __restrict__ Wr,
    const float* __restrict__ Wh,
    const float* __restrict__ whs, const float* __restrict__ uhs,
    unsigned short* __restrict__ Sbf,
    unsigned short* __restrict__ WTz, unsigned short* __restrict__ WTr,
    unsigned short* __restrict__ WTh,
    float* __restrict__ sphw, float* __restrict__ sphu)
{
  const int blk = blockIdx.x, t = threadIdx.x;

  if (blk < 2048) {  // ---- S -> bf16 (R1 verbatim) ----
    const f4* S4 = (const f4*)S;
    us4* O4 = (us4*)Sbf;
    const int base = blk * 256 + t;
#pragma unroll
    for (int i = 0; i < 4; ++i) {
      int idx = base + i * 524288;
      f4 v = S4[idx];
      us4 o;
      o[0] = f2bf(v[0]); o[1] = f2bf(v[1]); o[2] = f2bf(v[2]); o[3] = f2bf(v[3]);
      O4[idx] = o;
    }
    return;
  }

  if (blk < 2144) {  // ---- WT build: WT[n][k] = bf16(W[k][n]) ----
    const int q = blk - 2048;           // 0..95
    const int g = q >> 5, kc = q & 31;  // 32 k-chunks of 8
    const float* W = (g == 0) ? Wz : ((g == 1) ? Wr : Wh);
    unsigned short* WT = (g == 0) ? WTz : ((g == 1) ? WTr : WTh);
    const int n = t;
    us4 a, b;
#pragma unroll
    for (int e = 0; e < 4; ++e) a[e] = f2bf(W[(kc * 8 + e) * 256 + n]);
#pragma unroll
    for (int e = 0; e < 4; ++e) b[e] = f2bf(W[(kc * 8 + 4 + e) * 256 + n]);
    *reinterpret_cast<us4*>(WT + n * 256 + kc * 8) = a;
    *reinterpret_cast<us4*>(WT + n * 256 + kc * 8 + 4) = b;
    return;
  }

  // ---- softplus vectors (gate h epilogue) ----
  sphw[t] = log1pf(expf(whs[t]));
  sphu[t] = log1pf(expf(uhs[t]));
}

// ---------------------------------------------------------------------------
// mean: one block per batch, R1's f32 formulas; weights k-tiled through LDS
// (coalesced f4 loads) so the 512-deep dot products are latency-tolerant.
// Produces z, r, h derivatives, diagz/diagr, mu, sx, ssr.
// ---------------------------------------------------------------------------
__global__ __launch_bounds__(256) void mean_kernel(
    const float* __restrict__ xin, const float* __restrict__ prev,
    const float* __restrict__ S,
    const float* __restrict__ Uz, const float* __restrict__ Wz,
    const float* __restrict__ uzs, const float* __restrict__ wzs,
    const float* __restrict__ Ur, const float* __restrict__ Wr,
    const float* __restrict__ urs, const float* __restrict__ wrs,
    const float* __restrict__ Uh, const float* __restrict__ Wh,
    float* __restrict__ zv, float* __restrict__ rv,
    float* __restrict__ gzv, float* __restrict__ grv,
    float* __restrict__ ghv, float* __restrict__ pmhv,
    float* __restrict__ diagz, float* __restrict__ diagr,
    float* __restrict__ muOut,
    float* __restrict__ sxA, float* __restrict__ ssrA)
{
  const int b = blockIdx.x, t = threadIdx.x;
  __shared__ float xs[256], ps[256], srs[256];
  __shared__ __align__(16) float wA[32][260];  // 260 pad: f4-aligned rows
  __shared__ __align__(16) float wB[32][260];
  __shared__ float red[4];

  auto bred = [&](float v) -> float {  // R1-verbatim block reduction
#pragma unroll
    for (int off = 32; off; off >>= 1) v += __shfl_down(v, off, 64);
    __syncthreads();
    if ((t & 63) == 0) red[t >> 6] = v;
    __syncthreads();
    return red[0] + red[1] + red[2] + red[3];
  };

  xs[t] = xin[b * 256 + t];
  ps[t] = prev[b * 256 + t];
  __syncthreads();

  // ---- z & r: m = [x|p] . [U;W] ----
  float mz = 0.f, mr = 0.f;
  for (int kt = 0; kt < 16; ++kt) {
    const int k0 = kt * 32;
    const float* MZ = (k0 < 256) ? (Uz + k0 * 256) : (Wz + (k0 - 256) * 256);
    const float* MR = (k0 < 256) ? (Ur + k0 * 256) : (Wr + (k0 - 256) * 256);
    __syncthreads();  // previous tile fully consumed
#pragma unroll
    for (int i = 0; i < 8; ++i) {
      int e = t + i * 256;              // f4 index in [0,2048): 32 rows x 64 f4
      int rr = e >> 6, c4 = e & 63;
      *reinterpret_cast<f4*>(&wA[rr][c4 * 4]) = reinterpret_cast<const f4*>(MZ)[e];
      *reinterpret_cast<f4*>(&wB[rr][c4 * 4]) = reinterpret_cast<const f4*>(MR)[e];
    }
    __syncthreads();
    const float* xp = (k0 < 256) ? &xs[k0] : &ps[k0 - 256];
#pragma unroll
    for (int k = 0; k < 32; ++k) {
      float xv = xp[k];
      mz = fmaf(xv, wA[k][t], mz);
      mr = fmaf(xv, wB[k][t], mr);
    }
  }
  const float z = 1.f / (1.f + expf(-mz));
  const float r = 1.f / (1.f + expf(-mr));
  srs[t] = ps[t] * r;
  __syncthreads();

  // ---- h: m_h = [x|sr] . [Uh;Wh] ----
  float mh = 0.f;
  for (int kt = 0; kt < 16; ++kt) {
    const int k0 = kt * 32;
    const float* MH = (k0 < 256) ? (Uh + k0 * 256) : (Wh + (k0 - 256) * 256);
    __syncthreads();
#pragma unroll
    for (int i = 0; i < 8; ++i) {
      int e = t + i * 256;
      int rr = e >> 6, c4 = e & 63;
      *reinterpret_cast<f4*>(&wA[rr][c4 * 4]) = reinterpret_cast<const f4*>(MH)[e];
    }
    __syncthreads();
    const float* xp = (k0 < 256) ? &xs[k0] : &srs[k0 - 256];
#pragma unroll
    for (int k = 0; k < 32; ++k) mh = fmaf(xp[k], wA[k][t], mh);
  }
  const float h = tanhf(mh);

  // ---- reductions (R1-verbatim formulas) ----
  float sx  = bred(xs[t] * xs[t]);
  float sp  = bred(ps[t] * ps[t]);
  float trS = bred(S[(size_t)b * 65536 + (size_t)t * 257]);
  float ssr = bred(srs[t] * srs[t]);

  float spwz = log1pf(expf(wzs[t])), spuz = log1pf(expf(uzs[t]));
  float spwr = log1pf(expf(wrs[t])), spur = log1pf(expf(urs[t]));

  const int idx = b * 256 + t;
  zv[idx] = z;            rv[idx] = r;
  gzv[idx] = z * (1.f - z);
  grv[idx] = r * (1.f - r);
  ghv[idx] = 1.f - h * h;
  pmhv[idx] = ps[t] - h;
  diagz[idx] = (sp + trS) * spwz + sx * spuz;
  diagr[idx] = (sp + trS) * spwr + sx * spur;
  muOut[idx] = z * ps[t] + (1.f - z) * h;
  if (t == 0) { sxA[b] = sx; ssrA[b] = ssr; }
}

// ---------------------------------------------------------------------------
// gate_kernel<GATE> — R1's exact passing tiling (4 waves, Tt[64][264]).
// GATE 0: Sigma_z -> Szbf (bf16).  GATE 1: sigma_g -> sg (bf16) + trace
// partials (wave==nb).  GATE 2: Sigma_out -> fOut (f32), in-kernel evd.
// ---------------------------------------------------------------------------
template <int GATE>
__global__ __launch_bounds__(256) void gate_kernel(
    const unsigned short* __restrict__ Amat,   // Sbf (0,1) / sg (2)
    const unsigned short* __restrict__ WT,
    const unsigned short* __restrict__ Sb,     // Sbf epilogue (1,2)
    const unsigned short* __restrict__ Szb,    // Szbf (2)
    const float* __restrict__ v1,              // gzv / grv / ghv
    const float* __restrict__ dvec,            // diagz / diagr / -
    const float* __restrict__ v2,              // -    / prev  / zv
    const float* __restrict__ v3,              // -    / rv    / pmhv
    const float* __restrict__ sphw, const float* __restrict__ sphu,
    const float* __restrict__ sxA, const float* __restrict__ ssrA,
    const float* __restrict__ trsgIn,
    float* __restrict__ fOut, unsigned short* __restrict__ bOut,
    float* __restrict__ trsgOut)
{
  __shared__ unsigned short Tt[64][264];  // T^T, row stride 528B (16B-aligned)
  __shared__ float ev0[256], evd[256], ev2[256], ev3[256];

  const int blk = blockIdx.x, tid = threadIdx.x;
  const int wave = tid >> 6, lane = tid & 63, lhi = lane >> 4, l15 = lane & 15;
  const int b = blk >> 2, nb = blk & 3, col0 = nb * 64;
  const size_t bb = (size_t)b << 16;
  const f4 z4 = {0.f, 0.f, 0.f, 0.f};

  {  // epilogue vectors
    const int u = tid;
    ev0[u] = v1[b * 256 + u];
    if constexpr (GATE == 2) {
      float trsg = trsgIn[b * 4] + trsgIn[b * 4 + 1]
                 + trsgIn[b * 4 + 2] + trsgIn[b * 4 + 3];
      evd[u] = (ssrA[b] + trsg) * sphw[u] + sxA[b] * sphu[u];
    } else {
      evd[u] = dvec[b * 256 + u];
    }
    if constexpr (GATE >= 1) {
      ev2[u] = v2[b * 256 + u];
      ev3[u] = v3[b * 256 + u];
    }
  }

  f4 acc[4][4];
#pragma unroll
  for (int i = 0; i < 4; ++i)
#pragma unroll
    for (int j = 0; j < 4; ++j) acc[i][j] = z4;

  // ---------------- stage 1: T = A_b @ W[:,col0:+64) ----------------
  const unsigned short* Ab = Amat + bb;
  const int kb = lhi * 8;
#pragma unroll
  for (int kt = 0; kt < 8; ++kt) {
    const int k = kt * 32 + kb;
    sh8 af[4], bfr[4];
#pragma unroll
    for (int rt = 0; rt < 4; ++rt)
      af[rt] = *reinterpret_cast<const sh8*>(Ab + ((wave * 64 + rt * 16 + l15) << 8) + k);
#pragma unroll
    for (int ct = 0; ct < 4; ++ct)
      bfr[ct] = *reinterpret_cast<const sh8*>(WT + ((col0 + ct * 16 + l15) << 8) + k);
#pragma unroll
    for (int rt = 0; rt < 4; ++rt)
#pragma unroll
      for (int ct = 0; ct < 4; ++ct)
        acc[rt][ct] = mfma16(af[rt], bfr[ct], acc[rt][ct]);
  }

  // T^T (bf16, software RNE) -> LDS
#pragma unroll
  for (int rt = 0; rt < 4; ++rt) {
    const int row0 = wave * 64 + rt * 16 + lhi * 4;
#pragma unroll
    for (int ct = 0; ct < 4; ++ct) {
      const int c = ct * 16 + l15;
      us4 p4;
      p4[0] = f2bf(acc[rt][ct][0]); p4[1] = f2bf(acc[rt][ct][1]);
      p4[2] = f2bf(acc[rt][ct][2]); p4[3] = f2bf(acc[rt][ct][3]);
      *reinterpret_cast<us4*>(&Tt[c][row0]) = p4;
    }
  }
  __syncthreads();

#pragma unroll
  for (int i = 0; i < 4; ++i)
#pragma unroll
    for (int j = 0; j < 4; ++j) acc[i][j] = z4;

  // ---------------- stage 2: Y = W^T @ T ----------------
#pragma unroll
  for (int jt = 0; jt < 8; ++jt) {
    const int j = jt * 32 + kb;
    sh8 af[4], bfr[4];
#pragma unroll
    for (int rt = 0; rt < 4; ++rt)
      af[rt] = *reinterpret_cast<const sh8*>(WT + ((wave * 64 + rt * 16 + l15) << 8) + j);
#pragma unroll
    for (int ct = 0; ct < 4; ++ct)
      bfr[ct] = *reinterpret_cast<const sh8*>(&Tt[ct * 16 + l15][j]);
#pragma unroll
    for (int rt = 0; rt < 4; ++rt)
#pragma unroll
      for (int ct = 0; ct < 4; ++ct)
        acc[rt][ct] = mfma16(af[rt], bfr[ct], acc[rt][ct]);
  }

  // ---------------- epilogue ----------------
  float trloc = 0.f;
#pragma unroll
  for (int rt = 0; rt < 4; ++rt) {
    const int i0 = wave * 64 + rt * 16 + lhi * 4;
#pragma unroll
    for (int ct = 0; ct < 4; ++ct) {
      const int j = col0 + ct * 16 + l15;
#pragma unroll
      for (int rr = 0; rr < 4; ++rr) {
        const int i = i0 + rr;
        const size_t idx = bb + ((size_t)i << 8) + j;
        float Y = acc[rt][ct][rr] + ((i == j) ? evd[i] : 0.f);
        if constexpr (GATE == 0) {
          bOut[idx] = f2bf(Y * ev0[i] * ev0[j]);
        } else if constexpr (GATE == 1) {
          float Sr = Y * ev0[i] * ev0[j];
          float Sv = bf2f(Sb[idx]);
          float sgv = Sr * (Sv + ev2[i] * ev2[j]) + ev3[i] * ev3[j] * Sv;
          bOut[idx] = f2bf(sgv);
          if (i == j) trloc += sgv;
        } else {
          float Sh = Y * ev0[i] * ev0[j];
          float Sv = bf2f(Sb[idx]);
          float Szv = bf2f(Szb[idx]);
          fOut[idx] = Szv * (Sv + Sh + ev3[i] * ev3[j])
                    + Sv * ev2[i] * ev2[j]
                    + Sh * (1.f - ev2[i]) * (1.f - ev2[j]);
        }
      }
    }
  }

  if constexpr (GATE == 1) {  // deterministic trace partials (R2-proven)
    if (wave == nb) {
#pragma unroll
      for (int off = 32; off; off >>= 1) trloc += __shfl_down(trloc, off, 64);
      if (lane == 0) trsgOut[b * 4 + nb] = trloc;
    }
  }
}

// ---------------------------------------------------------------------------
extern "C" void kernel_launch(void* const* d_in, const int* in_sizes, int n_in,
                              void* d_out, int out_size, void* d_ws, size_t ws_size,
                              hipStream_t stream)
{
  const float* xin  = (const float*)d_in[0];
  const float* prev = (const float*)d_in[1];
  const float* S    = (const float*)d_in[2];
  const float* Uz = (const float*)d_in[3];  const float* uzs = (const float*)d_in[4];
  const float* Wz = (const float*)d_in[5];  const float* wzs = (const float*)d_in[6];
  const float* Ur = (const float*)d_in[7];  const float* urs = (const float*)d_in[8];
  const float* Wr = (const float*)d_in[9];  const float* wrs = (const float*)d_in[10];
  const float* Uh = (const float*)d_in[11]; const float* uhs = (const float*)d_in[12];
  const float* Wh = (const float*)d_in[13]; const float* whs = (const float*)d_in[14];

  float* muOut  = (float*)d_out;
  float* SigOut = muOut + 128 * 256;

  char* p = (char*)d_ws;
  auto take = [&](size_t bytes) { void* q = (void*)p; p += bytes; return q; };
  unsigned short* Sbf  = (unsigned short*)take(16777216);  // S bf16
  unsigned short* sg   = (unsigned short*)take(16777216);  // sigma_g bf16
  unsigned short* Szbf = (unsigned short*)take(16777216);  // Sigma_z bf16
  unsigned short* WTz  = (unsigned short*)take(131072);
  unsigned short* WTr  = (unsigned short*)take(131072);
  unsigned short* WTh  = (unsigned short*)take(131072);
  float* zv    = (float*)take(131072);
  float* rv    = (float*)take(131072);
  float* gzv   = (float*)take(131072);
  float* grv   = (float*)take(131072);
  float* ghv   = (float*)take(131072);
  float* pmhv  = (float*)take(131072);
  float* diagz = (float*)take(131072);
  float* diagr = (float*)take(131072);
  float* sphw  = (float*)take(1024);
  float* sphu  = (float*)take(1024);
  float* sxA   = (float*)take(512);
  float* ssrA  = (float*)take(512);
  float* trsgP = (float*)take(2048);
  (void)in_sizes; (void)n_in; (void)out_size; (void)ws_size;

  prep_kernel<<<2145, 256, 0, stream>>>(
      S, Wz, Wr, Wh, whs, uhs, Sbf, WTz, WTr, WTh, sphw, sphu);

  mean_kernel<<<128, 256, 0, stream>>>(
      xin, prev, S, Uz, Wz, uzs, wzs, Ur, Wr, urs, wrs, Uh, Wh,
      zv, rv, gzv, grv, ghv, pmhv, diagz, diagr, muOut, sxA, ssrA);

  gate_kernel<0><<<512, 256, 0, stream>>>(
      Sbf, WTz, nullptr, nullptr, gzv, diagz, nullptr, nullptr,
      sphw, sphu, sxA, ssrA, nullptr,
      nullptr, Szbf, nullptr);

  gate_kernel<1><<<512, 256, 0, stream>>>(
      Sbf, WTr, Sbf, nullptr, grv, diagr, prev, rv,
      sphw, sphu, sxA, ssrA, nullptr,
      nullptr, sg, trsgP);

  gate_kernel<2><<<512, 256, 0, stream>>>(
      sg, WTh, Sbf, Szbf, ghv, nullptr, zv, pmhv,
      sphw, sphu, sxA, ssrA, trsgP,
      SigOut, nullptr, nullptr);
}

// Round 6
// 115.065 us; speedup vs baseline: 2.1546x; 1.3064x over previous
//
#include <hip/hip_runtime.h>
#include <math.h>

// densityPropGRUCell on MI355X (gfx950).  B=128, U=D=256.
// R6: 3 launches.  All bf16 packing via software f2bf (cvt2 banned: R4's
// failure correlates with mixed cvt2/f2bf operand packing).
//  K1 prep : S -> Sfrag (MFMA-fragment-ordered bf16), pack1/pack2 for all
//            gates (R2-proven builder), per-batch reductions, softplus
//            vectors, mean1 (z,r) as column-parallel f32 GEMV.
//  K2 fuse : mean2 (h,gh,pmh,mu,ssr) + gate0 (Sigma_z->Szbf) + gate1
//            (sigma_g -> sgf fragment-ordered + trace partials).
//  K3 gateh: Sigma_out (perfect-square epilogue) -> d_out.

typedef __attribute__((ext_vector_type(8))) short sh8;           // 8 x bf16
typedef __attribute__((ext_vector_type(4))) float f4;
typedef __attribute__((ext_vector_type(4))) unsigned short us4;  // 4 x bf16

__device__ __forceinline__ unsigned short f2bf(float f) {  // software RNE
  unsigned int u = __float_as_uint(f);
  u = (u + 0x7fffu + ((u >> 16) & 1u)) >> 16;
  return (unsigned short)u;
}
__device__ __forceinline__ float bf2f(unsigned short u) {
  return __uint_as_float(((unsigned int)u) << 16);
}
__device__ __forceinline__ f4 mfma16(sh8 a, sh8 b, f4 c) {
  return __builtin_amdgcn_mfma_f32_16x16x32_bf16(a, b, c, 0, 0, 0);
}

// Fragment chunk layout (shared by Sfrag writer, sgf writer, gate readers):
// chunk ci = b*128 + kt*16 + R  (R = row-group, kt = k-tile of 32)
// lane l of chunk holds M[b][R*16 + (l&15)][kt*32 + (l>>4)*8 + e], e=0..7.
// short offset = (ci<<9) + lane*8.

// ---------------------------------------------------------------------------
// K1 prep.
//  [0,2048)    : S -> Sfrag   (b = blk>>4, R = blk&15)
//  [2048,2096) : pack builder (R2-verbatim, 6 packs of 128KB)
//  [2096,2224) : per-batch reductions sx, sp, trS
//  2224        : softplus vectors (all 6)
//  [2225,2481) : mean1 z/r  (g = q>>7, b = q&127; thread = column)
// ---------------------------------------------------------------------------
__global__ __launch_bounds__(256) void prep_kernel(
    const float* __restrict__ xin, const float* __restrict__ prev,
    const float* __restrict__ S,
    const float* __restrict__ Uz, const float* __restrict__ Wz,
    const float* __restrict__ uzs, const float* __restrict__ wzs,
    const float* __restrict__ Ur, const float* __restrict__ Wr,
    const float* __restrict__ urs, const float* __restrict__ wrs,
    const float* __restrict__ Uh, const float* __restrict__ Wh,
    const float* __restrict__ uhs, const float* __restrict__ whs,
    unsigned short* __restrict__ Sfrag, unsigned short* __restrict__ packs,
    float* __restrict__ spzw, float* __restrict__ spzu,
    float* __restrict__ sprw, float* __restrict__ spru,
    float* __restrict__ sphw, float* __restrict__ sphu,
    float* __restrict__ sxA, float* __restrict__ spA, float* __restrict__ trSA,
    float* __restrict__ zv, float* __restrict__ rv,
    float* __restrict__ gzv, float* __restrict__ grv)
{
  const int blk = blockIdx.x, t = threadIdx.x;
  __shared__ float Srows[16][260];        // 16.6 KB, padded (2-way max)
  __shared__ float xs[256], ps[256];

  if (blk < 2048) {  // ---- S -> Sfrag ----
    const int b = blk >> 4, R = blk & 15;
    const float* Sb = S + ((size_t)b << 16) + (size_t)(R * 16) * 256;
#pragma unroll
    for (int i = 0; i < 4; ++i) {
      int e = t + i * 256;                // f4 index over 16x256 floats
      int row = e >> 6, c4 = e & 63;
      f4 v = reinterpret_cast<const f4*>(Sb)[e];
      *reinterpret_cast<f4*>(&Srows[row][c4 * 4]) = v;
    }
    __syncthreads();
    unsigned short* outb = Sfrag + ((size_t)b << 16) + R * 512;
#pragma unroll
    for (int qi = 0; qi < 2; ++qi) {
      int q = t + qi * 256;               // (kt,lane) combo, 0..511
      int kt = q >> 6, lane = q & 63;
      int l15 = lane & 15, c0 = kt * 32 + (lane >> 4) * 8;
      union { unsigned short u[8]; uint4 v; } pk;
#pragma unroll
      for (int e = 0; e < 8; ++e) pk.u[e] = f2bf(Srows[l15][c0 + e]);
      *reinterpret_cast<uint4*>(outb + kt * 8192 + lane * 8) = pk.v;
    }
    return;
  }

  if (blk < 2096) {  // ---- pack builder (R2-proven) ----
    int gid = (blk - 2048) * 256 + t;
#pragma unroll
    for (int q2 = 0; q2 < 4; ++q2) {
      int cid = gid * 4 + q2;             // 0..49151
      int p = cid >> 13, c = cid & 8191;
      const float* W = (p >> 1) == 0 ? Wz : ((p >> 1) == 1 ? Wr : Wh);
      int lane = c & 63, l15 = lane & 15, lhi = lane >> 4;
      int n, k8;
      if ((p & 1) == 0) {                 // pack1 (stage-1 B)
        int nb = (c >> 11) & 3, kt = (c >> 8) & 7, ct = (c >> 6) & 3;
        n = nb * 64 + ct * 16 + l15; k8 = kt * 32 + lhi * 8;
      } else {                            // pack2 (stage-2 A)
        int wv = (c >> 11) & 3, rt = (c >> 9) & 3, jt = (c >> 6) & 7;
        n = wv * 64 + rt * 16 + l15; k8 = jt * 32 + lhi * 8;
      }
      union { unsigned short u[8]; uint4 v; } pk;
#pragma unroll
      for (int e = 0; e < 8; ++e) pk.u[e] = f2bf(W[(k8 + e) * 256 + n]);
      *reinterpret_cast<uint4*>(packs + (size_t)p * 65536 + (size_t)c * 8) = pk.v;
    }
    return;
  }

  if (blk < 2224) {  // ---- per-batch reductions (R5 verbatim) ----
    const int b = blk - 2096;
    __shared__ float red[12];
    float x = xin[b * 256 + t];
    float p = prev[b * 256 + t];
    float d = S[(size_t)b * 65536 + (size_t)t * 257];
    float a0 = x * x, a1 = p * p, a2 = d;
#pragma unroll
    for (int off = 32; off; off >>= 1) {
      a0 += __shfl_down(a0, off, 64);
      a1 += __shfl_down(a1, off, 64);
      a2 += __shfl_down(a2, off, 64);
    }
    if ((t & 63) == 0) {
      int w = t >> 6;
      red[w] = a0; red[4 + w] = a1; red[8 + w] = a2;
    }
    __syncthreads();
    if (t == 0) {
      sxA[b] = red[0] + red[1] + red[2] + red[3];
      spA[b] = red[4] + red[5] + red[6] + red[7];
      trSA[b] = red[8] + red[9] + red[10] + red[11];
    }
    return;
  }

  if (blk == 2224) {  // ---- softplus ----
    spzw[t] = log1pf(expf(wzs[t])); spzu[t] = log1pf(expf(uzs[t]));
    sprw[t] = log1pf(expf(wrs[t])); spru[t] = log1pf(expf(urs[t]));
    sphw[t] = log1pf(expf(whs[t])); sphu[t] = log1pf(expf(uhs[t]));
    return;
  }

  // ---- mean1: m_g[b][t] = x_b . U_g[:,t] + p_b . W_g[:,t]  (f32) ----
  const int q = blk - 2225, g = q >> 7, b = q & 127;
  xs[t] = xin[b * 256 + t];
  ps[t] = prev[b * 256 + t];
  __syncthreads();
  const float* U = g ? Ur : Uz;
  const float* W = g ? Wr : Wz;
  float a0 = 0.f, a1 = 0.f, a2 = 0.f, a3 = 0.f;
  for (int k = 0; k < 256; k += 4) {
    a0 = fmaf(xs[k],     U[(k)     * 256 + t], a0);
    a1 = fmaf(xs[k + 1], U[(k + 1) * 256 + t], a1);
    a2 = fmaf(xs[k + 2], U[(k + 2) * 256 + t], a2);
    a3 = fmaf(xs[k + 3], U[(k + 3) * 256 + t], a3);
  }
  for (int k = 0; k < 256; k += 4) {
    a0 = fmaf(ps[k],     W[(k)     * 256 + t], a0);
    a1 = fmaf(ps[k + 1], W[(k + 1) * 256 + t], a1);
    a2 = fmaf(ps[k + 2], W[(k + 2) * 256 + t], a2);
    a3 = fmaf(ps[k + 3], W[(k + 3) * 256 + t], a3);
  }
  const float m = (a0 + a1) + (a2 + a3);
  const float zz = 1.f / (1.f + expf(-m));
  const int idx = b * 256 + t;
  if (g == 0) { zv[idx] = zz; gzv[idx] = zz * (1.f - zz); }
  else        { rv[idx] = zz; grv[idx] = zz * (1.f - zz); }
}

// ---------------------------------------------------------------------------
// K2 fuse.
//  [0,128)    : mean2 (h, gh, pmh, mu, ssr)
//  [128,640)  : gate0 Sigma_z -> Szbf (linear bf16)
//  [640,1152) : gate1 sigma_g -> sgf (fragment order) + trace partials
// ---------------------------------------------------------------------------
__global__ __launch_bounds__(256) void fuse_kernel(
    const float* __restrict__ xin, const float* __restrict__ prev,
    const float* __restrict__ S,
    const float* __restrict__ Uh, const float* __restrict__ Wh,
    const float* __restrict__ zv, const float* __restrict__ rv,
    const float* __restrict__ gzv, const float* __restrict__ grv,
    const unsigned short* __restrict__ packs,
    const unsigned short* __restrict__ Sfrag,
    const float* __restrict__ spzw, const float* __restrict__ spzu,
    const float* __restrict__ sprw, const float* __restrict__ spru,
    const float* __restrict__ sxA, const float* __restrict__ spA,
    const float* __restrict__ trSA,
    unsigned short* __restrict__ Szbf, unsigned short* __restrict__ sgf,
    float* __restrict__ trsgP,
    float* __restrict__ ghv, float* __restrict__ pmhv,
    float* __restrict__ muOut, float* __restrict__ ssrA)
{
  __shared__ unsigned short Tt[64][264];
  __shared__ float ev0[256], evd[256], ev2[256], ev3[256];

  const int blk = blockIdx.x, tid = threadIdx.x;
  const f4 z4 = {0.f, 0.f, 0.f, 0.f};

  if (blk < 128) {  // ---- mean2 ----
    float* xs  = (float*)&Tt[0][0];
    float* ps  = xs + 256;
    float* srs = ps + 256;
    float* red = srs + 256;
    const int b = blk, t = tid;
    xs[t] = xin[b * 256 + t];
    float pv = prev[b * 256 + t];
    ps[t] = pv;
    srs[t] = pv * rv[b * 256 + t];
    __syncthreads();
    float a0 = 0.f, a1 = 0.f, a2 = 0.f, a3 = 0.f;
    for (int k = 0; k < 256; k += 4) {
      a0 = fmaf(xs[k],     Uh[(k)     * 256 + t], a0);
      a1 = fmaf(xs[k + 1], Uh[(k + 1) * 256 + t], a1);
      a2 = fmaf(xs[k + 2], Uh[(k + 2) * 256 + t], a2);
      a3 = fmaf(xs[k + 3], Uh[(k + 3) * 256 + t], a3);
    }
    for (int k = 0; k < 256; k += 4) {
      a0 = fmaf(srs[k],     Wh[(k)     * 256 + t], a0);
      a1 = fmaf(srs[k + 1], Wh[(k + 1) * 256 + t], a1);
      a2 = fmaf(srs[k + 2], Wh[(k + 2) * 256 + t], a2);
      a3 = fmaf(srs[k + 3], Wh[(k + 3) * 256 + t], a3);
    }
    const float m = (a0 + a1) + (a2 + a3);
    const float h = tanhf(m);
    const int idx = b * 256 + t;
    const float z = zv[idx];
    ghv[idx]  = 1.f - h * h;
    pmhv[idx] = pv - h;
    muOut[idx] = z * pv + (1.f - z) * h;
    // ssr reduction
    float s = srs[t] * srs[t];
#pragma unroll
    for (int off = 32; off; off >>= 1) s += __shfl_down(s, off, 64);
    __syncthreads();
    if ((t & 63) == 0) red[t >> 6] = s;
    __syncthreads();
    if (t == 0) ssrA[b] = red[0] + red[1] + red[2] + red[3];
    return;
  }

  // ---- gate0 / gate1 ----
  const int isR = (blk >= 640);
  const int q = isR ? (blk - 640) : (blk - 128);
  const int b = q >> 2, nb = q & 3, col0 = nb * 64;
  const int wave = tid >> 6, lane = tid & 63, lhi = lane >> 4, l15 = lane & 15;
  const size_t bb = (size_t)b << 16;
  const unsigned short* p1 = packs + (size_t)(isR ? 2 : 0) * 65536;
  const unsigned short* p2 = packs + (size_t)(isR ? 3 : 1) * 65536;

  {  // epilogue vectors + in-kernel diag
    const int u = tid;
    const float sd = spA[b] + trSA[b], sx = sxA[b];
    if (isR) {
      ev0[u] = grv[b * 256 + u];
      evd[u] = sd * sprw[u] + sx * spru[u];
      ev2[u] = prev[b * 256 + u];
      ev3[u] = rv[b * 256 + u];
    } else {
      ev0[u] = gzv[b * 256 + u];
      evd[u] = sd * spzw[u] + sx * spzu[u];
    }
  }

  f4 acc[4][4];
#pragma unroll
  for (int i = 0; i < 4; ++i)
#pragma unroll
    for (int j = 0; j < 4; ++j) acc[i][j] = z4;

  // stage 1: T = S_b @ W[:,col0:+64)   (A from Sfrag, B from pack1)
  const unsigned short* Af = Sfrag + bb;
#pragma unroll
  for (int kt = 0; kt < 8; ++kt) {
    sh8 af[4], bfr[4];
#pragma unroll
    for (int rt = 0; rt < 4; ++rt)
      af[rt] = *reinterpret_cast<const sh8*>(
          Af + kt * 8192 + (wave * 4 + rt) * 512 + lane * 8);
#pragma unroll
    for (int ct = 0; ct < 4; ++ct)
      bfr[ct] = *reinterpret_cast<const sh8*>(
          p1 + ((size_t)(((nb * 8 + kt) * 4 + ct) * 64 + lane) << 3));
#pragma unroll
    for (int rt = 0; rt < 4; ++rt)
#pragma unroll
      for (int ct = 0; ct < 4; ++ct)
        acc[rt][ct] = mfma16(af[rt], bfr[ct], acc[rt][ct]);
  }

  // T^T (bf16) -> LDS
#pragma unroll
  for (int rt = 0; rt < 4; ++rt) {
    const int row0 = wave * 64 + rt * 16 + lhi * 4;
#pragma unroll
    for (int ct = 0; ct < 4; ++ct) {
      const int c = ct * 16 + l15;
      us4 p4;
      p4[0] = f2bf(acc[rt][ct][0]); p4[1] = f2bf(acc[rt][ct][1]);
      p4[2] = f2bf(acc[rt][ct][2]); p4[3] = f2bf(acc[rt][ct][3]);
      *reinterpret_cast<us4*>(&Tt[c][row0]) = p4;
    }
  }
  __syncthreads();

#pragma unroll
  for (int i = 0; i < 4; ++i)
#pragma unroll
    for (int j = 0; j < 4; ++j) acc[i][j] = z4;

  // stage 2: Y = W^T @ T   (A from pack2, B from Tt)
#pragma unroll
  for (int jt = 0; jt < 8; ++jt) {
    const int j8 = jt * 32 + lhi * 8;
    sh8 af[4], bfr[4];
#pragma unroll
    for (int rt = 0; rt < 4; ++rt)
      af[rt] = *reinterpret_cast<const sh8*>(
          p2 + ((size_t)(((wave * 4 + rt) * 8 + jt) * 64 + lane) << 3));
#pragma unroll
    for (int ct = 0; ct < 4; ++ct)
      bfr[ct] = *reinterpret_cast<const sh8*>(&Tt[ct * 16 + l15][j8]);
#pragma unroll
    for (int rt = 0; rt < 4; ++rt)
#pragma unroll
      for (int ct = 0; ct < 4; ++ct)
        acc[rt][ct] = mfma16(af[rt], bfr[ct], acc[rt][ct]);
  }

  // epilogue
  float trloc = 0.f;
#pragma unroll
  for (int rt = 0; rt < 4; ++rt) {
    const int i0 = wave * 64 + rt * 16 + lhi * 4;
#pragma unroll
    for (int ct = 0; ct < 4; ++ct) {
      const int j = col0 + ct * 16 + l15;
#pragma unroll
      for (int rr = 0; rr < 4; ++rr) {
        const int i = i0 + rr;
        const size_t idx = bb + ((size_t)i << 8) + j;
        float Y = acc[rt][ct][rr] + ((i == j) ? evd[i] : 0.f);
        if (!isR) {
          Szbf[idx] = f2bf(Y * ev0[i] * ev0[j]);
        } else {
          float Sr = Y * ev0[i] * ev0[j];
          float Sv = S[idx];
          float sgv = Sr * (Sv + ev2[i] * ev2[j]) + ev3[i] * ev3[j] * Sv;
          // fragment-ordered store for gate2's A operand
          size_t fo = bb + (size_t)((j >> 5) * 8192) + (size_t)((i >> 4) * 512)
                    + (size_t)((((j >> 3) & 3) * 16 + (i & 15)) * 8) + (j & 7);
          sgf[fo] = f2bf(sgv);
          if (i == j) trloc += sgv;
        }
      }
    }
  }

  if (isR) {  // deterministic trace partials
    if (wave == nb) {
#pragma unroll
      for (int off = 32; off; off >>= 1) trloc += __shfl_down(trloc, off, 64);
      if (lane == 0) trsgP[b * 4 + nb] = trloc;
    }
  }
}

// ---------------------------------------------------------------------------
// K3 gateh: Sigma_out.  A = sgf (fragment-ordered), B = pack1h/pack2h.
// ---------------------------------------------------------------------------
__global__ __launch_bounds__(256) void gateh_kernel(
    const float* __restrict__ S,
    const unsigned short* __restrict__ sgf,
    const unsigned short* __restrict__ packs,
    const unsigned short* __restrict__ Szb,
    const float* __restrict__ ghv, const float* __restrict__ zv,
    const float* __restrict__ pmhv,
    const float* __restrict__ sphw, const float* __restrict__ sphu,
    const float* __restrict__ sxA, const float* __restrict__ ssrA,
    const float* __restrict__ trsgIn,
    float* __restrict__ fOut)
{
  __shared__ unsigned short Tt[64][264];
  __shared__ float ev0[256], evd[256], ev2[256], ev3[256];

  const int blk = blockIdx.x, tid = threadIdx.x;
  const int wave = tid >> 6, lane = tid & 63, lhi = lane >> 4, l15 = lane & 15;
  const int b = blk >> 2, nb = blk & 3, col0 = nb * 64;
  const size_t bb = (size_t)b << 16;
  const f4 z4 = {0.f, 0.f, 0.f, 0.f};
  const unsigned short* p1 = packs + (size_t)4 * 65536;
  const unsigned short* p2 = packs + (size_t)5 * 65536;

  {
    const int u = tid;
    float trsg = trsgIn[b * 4] + trsgIn[b * 4 + 1]
               + trsgIn[b * 4 + 2] + trsgIn[b * 4 + 3];
    ev0[u] = ghv[b * 256 + u];
    evd[u] = (ssrA[b] + trsg) * sphw[u] + sxA[b] * sphu[u];
    ev2[u] = zv[b * 256 + u];
    ev3[u] = pmhv[b * 256 + u];
  }

  f4 acc[4][4];
#pragma unroll
  for (int i = 0; i < 4; ++i)
#pragma unroll
    for (int j = 0; j < 4; ++j) acc[i][j] = z4;

  const unsigned short* Af = sgf + bb;
#pragma unroll
  for (int kt = 0; kt < 8; ++kt) {
    sh8 af[4], bfr[4];
#pragma unroll
    for (int rt = 0; rt < 4; ++rt)
      af[rt] = *reinterpret_cast<const sh8*>(
          Af + kt * 8192 + (wave * 4 + rt) * 512 + lane * 8);
#pragma unroll
    for (int ct = 0; ct < 4; ++ct)
      bfr[ct] = *reinterpret_cast<const sh8*>(
          p1 + ((size_t)(((nb * 8 + kt) * 4 + ct) * 64 + lane) << 3));
#pragma unroll
    for (int rt = 0; rt < 4; ++rt)
#pragma unroll
      for (int ct = 0; ct < 4; ++ct)
        acc[rt][ct] = mfma16(af[rt], bfr[ct], acc[rt][ct]);
  }

#pragma unroll
  for (int rt = 0; rt < 4; ++rt) {
    const int row0 = wave * 64 + rt * 16 + lhi * 4;
#pragma unroll
    for (int ct = 0; ct < 4; ++ct) {
      const int c = ct * 16 + l15;
      us4 p4;
      p4[0] = f2bf(acc[rt][ct][0]); p4[1] = f2bf(acc[rt][ct][1]);
      p4[2] = f2bf(acc[rt][ct][2]); p4[3] = f2bf(acc[rt][ct][3]);
      *reinterpret_cast<us4*>(&Tt[c][row0]) = p4;
    }
  }
  __syncthreads();

#pragma unroll
  for (int i = 0; i < 4; ++i)
#pragma unroll
    for (int j = 0; j < 4; ++j) acc[i][j] = z4;

#pragma unroll
  for (int jt = 0; jt < 8; ++jt) {
    const int j8 = jt * 32 + lhi * 8;
    sh8 af[4], bfr[4];
#pragma unroll
    for (int rt = 0; rt < 4; ++rt)
      af[rt] = *reinterpret_cast<const sh8*>(
          p2 + ((size_t)(((wave * 4 + rt) * 8 + jt) * 64 + lane) << 3));
#pragma unroll
    for (int ct = 0; ct < 4; ++ct)
      bfr[ct] = *reinterpret_cast<const sh8*>(&Tt[ct * 16 + l15][j8]);
#pragma unroll
    for (int rt = 0; rt < 4; ++rt)
#pragma unroll
      for (int ct = 0; ct < 4; ++ct)
        acc[rt][ct] = mfma16(af[rt], bfr[ct], acc[rt][ct]);
  }

#pragma unroll
  for (int rt = 0; rt < 4; ++rt) {
    const int i0 = wave * 64 + rt * 16 + lhi * 4;
#pragma unroll
    for (int ct = 0; ct < 4; ++ct) {
      const int j = col0 + ct * 16 + l15;
#pragma unroll
      for (int rr = 0; rr < 4; ++rr) {
        const int i = i0 + rr;
        const size_t idx = bb + ((size_t)i << 8) + j;
        float Sh = (acc[rt][ct][rr] + ((i == j) ? evd[i] : 0.f)) * ev0[i] * ev0[j];
        float Sv = S[idx];
        float Szv = bf2f(Szb[idx]);
        fOut[idx] = Szv * (Sv + Sh + ev3[i] * ev3[j])
                  + Sv * ev2[i] * ev2[j]
                  + Sh * (1.f - ev2[i]) * (1.f - ev2[j]);
      }
    }
  }
}

// ---------------------------------------------------------------------------
extern "C" void kernel_launch(void* const* d_in, const int* in_sizes, int n_in,
                              void* d_out, int out_size, void* d_ws, size_t ws_size,
                              hipStream_t stream)
{
  const float* xin  = (const float*)d_in[0];
  const float* prev = (const float*)d_in[1];
  const float* S    = (const float*)d_in[2];
  const float* Uz = (const float*)d_in[3];  const float* uzs = (const float*)d_in[4];
  const float* Wz = (const float*)d_in[5];  const float* wzs = (const float*)d_in[6];
  const float* Ur = (const float*)d_in[7];  const float* urs = (const float*)d_in[8];
  const float* Wr = (const float*)d_in[9];  const float* wrs = (const float*)d_in[10];
  const float* Uh = (const float*)d_in[11]; const float* uhs = (const float*)d_in[12];
  const float* Wh = (const float*)d_in[13]; const float* whs = (const float*)d_in[14];

  float* muOut  = (float*)d_out;
  float* SigOut = muOut + 128 * 256;

  char* p = (char*)d_ws;
  auto take = [&](size_t bytes) { void* q = (void*)p; p += bytes; return q; };
  unsigned short* Sfrag = (unsigned short*)take(16777216);  // S, frag order
  unsigned short* sgf   = (unsigned short*)take(16777216);  // sigma_g, frag order
  unsigned short* Szbf  = (unsigned short*)take(16777216);  // Sigma_z, linear
  unsigned short* packs = (unsigned short*)take(786432);    // 6 x 128KB
  float* zv   = (float*)take(131072);
  float* rv   = (float*)take(131072);
  float* gzv  = (float*)take(131072);
  float* grv  = (float*)take(131072);
  float* ghv  = (float*)take(131072);
  float* pmhv = (float*)take(131072);
  float* spzw = (float*)take(1024);
  float* spzu = (float*)take(1024);
  float* sprw = (float*)take(1024);
  float* spru = (float*)take(1024);
  float* sphw = (float*)take(1024);
  float* sphu = (float*)take(1024);
  float* sxA  = (float*)take(512);
  float* spA  = (float*)take(512);
  float* trSA = (float*)take(512);
  float* ssrA = (float*)take(512);
  float* trsgP = (float*)take(2048);
  (void)in_sizes; (void)n_in; (void)out_size; (void)ws_size;

  prep_kernel<<<2481, 256, 0, stream>>>(
      xin, prev, S, Uz, Wz, uzs, wzs, Ur, Wr, urs, wrs, Uh, Wh, uhs, whs,
      Sfrag, packs, spzw, spzu, sprw, spru, sphw, sphu,
      sxA, spA, trSA, zv, rv, gzv, grv);

  fuse_kernel<<<1152, 256, 0, stream>>>(
      xin, prev, S, Uh, Wh, zv, rv, gzv, grv, packs, Sfrag,
      spzw, spzu, sprw, spru, sxA, spA, trSA,
      Szbf, sgf, trsgP, ghv, pmhv, muOut, ssrA);

  gateh_kernel<<<512, 256, 0, stream>>>(
      S, sgf, packs, Szbf, ghv, zv, pmhv, sphw, sphu,
      sxA, ssrA, trsgP, SigOut);
}

// Round 8
// 109.117 us; speedup vs baseline: 2.2721x; 1.0545x over previous
//
#include <hip/hip_runtime.h>
#include <math.h>

// densityPropGRUCell on MI355X (gfx950).  B=128, U=D=256.
// R8 = R6 (passing, 115us) VERBATIM + XCD-aware block remap ONLY.
// R7 bundled {remap, Sv-bf16 epilogue, 8-acc means} and failed the
// post-timing re-validation; this round isolates the remap (bit-identical
// per-block math to R6 -- only blockIdx->(batch,role) permutation changes)
// to capture the L2-locality win with zero numeric delta.
//  K1 prep : S -> Sfrag (frag-ordered), packs, reductions, softplus, mean1.
//  K2 fuse : mean2 (h) + gate0 (Sigma_z->Szbf) + gate1 (sigma_g->sgf + trace),
//            gate blocks XCD-grouped: all 8 roles of batch b on one XCD.
//  K3 gateh: Sigma_out -> d_out, XCD-grouped (4 roles of b on one XCD).

typedef __attribute__((ext_vector_type(8))) short sh8;           // 8 x bf16
typedef __attribute__((ext_vector_type(4))) float f4;
typedef __attribute__((ext_vector_type(4))) unsigned short us4;  // 4 x bf16

__device__ __forceinline__ unsigned short f2bf(float f) {  // software RNE
  unsigned int u = __float_as_uint(f);
  u = (u + 0x7fffu + ((u >> 16) & 1u)) >> 16;
  return (unsigned short)u;
}
__device__ __forceinline__ float bf2f(unsigned short u) {
  return __uint_as_float(((unsigned int)u) << 16);
}
__device__ __forceinline__ f4 mfma16(sh8 a, sh8 b, f4 c) {
  return __builtin_amdgcn_mfma_f32_16x16x32_bf16(a, b, c, 0, 0, 0);
}

// Fragment chunk layout: chunk (b, kt, R): lane l, elem e holds
// M[b][R*16 + (l&15)][kt*32 + (l>>4)*8 + e]; short offset = b<<16 | kt*8192
// | R*512 | lane*8.

// ---------------------------------------------------------------------------
// K1 prep.
//  [0,2048)    : S -> Sfrag   (b = blk>>4, R = blk&15)
//  [2048,2096) : pack builder (R2-proven)
//  [2096,2224) : per-batch reductions sx, sp, trS
//  2224        : softplus vectors
//  [2225,2481) : mean1 z/r (g = q>>7, b = q&127; thread = column)
// ---------------------------------------------------------------------------
__global__ __launch_bounds__(256) void prep_kernel(
    const float* __restrict__ xin, const float* __restrict__ prev,
    const float* __restrict__ S,
    const float* __restrict__ Uz, const float* __restrict__ Wz,
    const float* __restrict__ uzs, const float* __restrict__ wzs,
    const float* __restrict__ Ur, const float* __restrict__ Wr,
    const float* __restrict__ urs, const float* __restrict__ wrs,
    const float* __restrict__ Uh, const float* __restrict__ Wh,
    const float* __restrict__ uhs, const float* __restrict__ whs,
    unsigned short* __restrict__ Sfrag, unsigned short* __restrict__ packs,
    float* __restrict__ spzw, float* __restrict__ spzu,
    float* __restrict__ sprw, float* __restrict__ spru,
    float* __restrict__ sphw, float* __restrict__ sphu,
    float* __restrict__ sxA, float* __restrict__ spA, float* __restrict__ trSA,
    float* __restrict__ zv, float* __restrict__ rv,
    float* __restrict__ gzv, float* __restrict__ grv)
{
  const int blk = blockIdx.x, t = threadIdx.x;
  __shared__ float Srows[16][260];        // 16.6 KB, padded
  __shared__ float xs[256], ps[256];

  if (blk < 2048) {  // ---- S -> Sfrag ----
    const int b = blk >> 4, R = blk & 15;
    const float* Sb = S + ((size_t)b << 16) + (size_t)(R * 16) * 256;
#pragma unroll
    for (int i = 0; i < 4; ++i) {
      int e = t + i * 256;                // f4 index over 16x256 floats
      int row = e >> 6, c4 = e & 63;
      f4 v = reinterpret_cast<const f4*>(Sb)[e];
      *reinterpret_cast<f4*>(&Srows[row][c4 * 4]) = v;
    }
    __syncthreads();
    unsigned short* outb = Sfrag + ((size_t)b << 16) + R * 512;
#pragma unroll
    for (int qi = 0; qi < 2; ++qi) {
      int q = t + qi * 256;               // (kt,lane) combo, 0..511
      int kt = q >> 6, lane = q & 63;
      int l15 = lane & 15, c0 = kt * 32 + (lane >> 4) * 8;
      union { unsigned short u[8]; uint4 v; } pk;
#pragma unroll
      for (int e = 0; e < 8; ++e) pk.u[e] = f2bf(Srows[l15][c0 + e]);
      *reinterpret_cast<uint4*>(outb + kt * 8192 + lane * 8) = pk.v;
    }
    return;
  }

  if (blk < 2096) {  // ---- pack builder (R2-proven) ----
    int gid = (blk - 2048) * 256 + t;
#pragma unroll
    for (int q2 = 0; q2 < 4; ++q2) {
      int cid = gid * 4 + q2;             // 0..49151
      int p = cid >> 13, c = cid & 8191;
      const float* W = (p >> 1) == 0 ? Wz : ((p >> 1) == 1 ? Wr : Wh);
      int lane = c & 63, l15 = lane & 15, lhi = lane >> 4;
      int n, k8;
      if ((p & 1) == 0) {                 // pack1 (stage-1 B)
        int nb = (c >> 11) & 3, kt = (c >> 8) & 7, ct = (c >> 6) & 3;
        n = nb * 64 + ct * 16 + l15; k8 = kt * 32 + lhi * 8;
      } else {                            // pack2 (stage-2 A)
        int wv = (c >> 11) & 3, rt = (c >> 9) & 3, jt = (c >> 6) & 7;
        n = wv * 64 + rt * 16 + l15; k8 = jt * 32 + lhi * 8;
      }
      union { unsigned short u[8]; uint4 v; } pk;
#pragma unroll
      for (int e = 0; e < 8; ++e) pk.u[e] = f2bf(W[(k8 + e) * 256 + n]);
      *reinterpret_cast<uint4*>(packs + (size_t)p * 65536 + (size_t)c * 8) = pk.v;
    }
    return;
  }

  if (blk < 2224) {  // ---- per-batch reductions (R5 verbatim) ----
    const int b = blk - 2096;
    __shared__ float red[12];
    float x = xin[b * 256 + t];
    float p = prev[b * 256 + t];
    float d = S[(size_t)b * 65536 + (size_t)t * 257];
    float a0 = x * x, a1 = p * p, a2 = d;
#pragma unroll
    for (int off = 32; off; off >>= 1) {
      a0 += __shfl_down(a0, off, 64);
      a1 += __shfl_down(a1, off, 64);
      a2 += __shfl_down(a2, off, 64);
    }
    if ((t & 63) == 0) {
      int w = t >> 6;
      red[w] = a0; red[4 + w] = a1; red[8 + w] = a2;
    }
    __syncthreads();
    if (t == 0) {
      sxA[b] = red[0] + red[1] + red[2] + red[3];
      spA[b] = red[4] + red[5] + red[6] + red[7];
      trSA[b] = red[8] + red[9] + red[10] + red[11];
    }
    return;
  }

  if (blk == 2224) {  // ---- softplus ----
    spzw[t] = log1pf(expf(wzs[t])); spzu[t] = log1pf(expf(uzs[t]));
    sprw[t] = log1pf(expf(wrs[t])); spru[t] = log1pf(expf(urs[t]));
    sphw[t] = log1pf(expf(whs[t])); sphu[t] = log1pf(expf(uhs[t]));
    return;
  }

  // ---- mean1: m_g[b][t] = x_b . U_g[:,t] + p_b . W_g[:,t]  (f32) ----
  const int q = blk - 2225, g = q >> 7, b = q & 127;
  xs[t] = xin[b * 256 + t];
  ps[t] = prev[b * 256 + t];
  __syncthreads();
  const float* U = g ? Ur : Uz;
  const float* W = g ? Wr : Wz;
  float a0 = 0.f, a1 = 0.f, a2 = 0.f, a3 = 0.f;
  for (int k = 0; k < 256; k += 4) {
    a0 = fmaf(xs[k],     U[(k)     * 256 + t], a0);
    a1 = fmaf(xs[k + 1], U[(k + 1) * 256 + t], a1);
    a2 = fmaf(xs[k + 2], U[(k + 2) * 256 + t], a2);
    a3 = fmaf(xs[k + 3], U[(k + 3) * 256 + t], a3);
  }
  for (int k = 0; k < 256; k += 4) {
    a0 = fmaf(ps[k],     W[(k)     * 256 + t], a0);
    a1 = fmaf(ps[k + 1], W[(k + 1) * 256 + t], a1);
    a2 = fmaf(ps[k + 2], W[(k + 2) * 256 + t], a2);
    a3 = fmaf(ps[k + 3], W[(k + 3) * 256 + t], a3);
  }
  const float m = (a0 + a1) + (a2 + a3);
  const float zz = 1.f / (1.f + expf(-m));
  const int idx = b * 256 + t;
  if (g == 0) { zv[idx] = zz; gzv[idx] = zz * (1.f - zz); }
  else        { rv[idx] = zz; grv[idx] = zz * (1.f - zz); }
}

// ---------------------------------------------------------------------------
// K2 fuse.
//  [0,128)     : mean2 (h, gh, pmh, mu, ssr)
//  [128,1152)  : gate0/gate1, XCD-grouped decode: q = blk-128,
//                c=q&7 (XCD), role=(q>>3)&7, chunk=q>>6, b=chunk*8+c,
//                isR=role>>2, nb=role&3.  Bijective (16*8*8=1024).
// ---------------------------------------------------------------------------
__global__ __launch_bounds__(256) void fuse_kernel(
    const float* __restrict__ xin, const float* __restrict__ prev,
    const float* __restrict__ S,
    const float* __restrict__ Uh, const float* __restrict__ Wh,
    const float* __restrict__ zv, const float* __restrict__ rv,
    const float* __restrict__ gzv, const float* __restrict__ grv,
    const unsigned short* __restrict__ packs,
    const unsigned short* __restrict__ Sfrag,
    const float* __restrict__ spzw, const float* __restrict__ spzu,
    const float* __restrict__ sprw, const float* __restrict__ spru,
    const float* __restrict__ sxA, const float* __restrict__ spA,
    const float* __restrict__ trSA,
    unsigned short* __restrict__ Szbf, unsigned short* __restrict__ sgf,
    float* __restrict__ trsgP,
    float* __restrict__ ghv, float* __restrict__ pmhv,
    float* __restrict__ muOut, float* __restrict__ ssrA)
{
  __shared__ unsigned short Tt[64][264];
  __shared__ float ev0[256], evd[256], ev2[256], ev3[256];

  const int blk = blockIdx.x, tid = threadIdx.x;
  const f4 z4 = {0.f, 0.f, 0.f, 0.f};

  if (blk < 128) {  // ---- mean2 ----
    float* xs  = (float*)&Tt[0][0];
    float* ps  = xs + 256;
    float* srs = ps + 256;
    float* red = srs + 256;
    const int b = blk, t = tid;
    xs[t] = xin[b * 256 + t];
    float pv = prev[b * 256 + t];
    ps[t] = pv;
    srs[t] = pv * rv[b * 256 + t];
    __syncthreads();
    float a0 = 0.f, a1 = 0.f, a2 = 0.f, a3 = 0.f;
    for (int k = 0; k < 256; k += 4) {
      a0 = fmaf(xs[k],     Uh[(k)     * 256 + t], a0);
      a1 = fmaf(xs[k + 1], Uh[(k + 1) * 256 + t], a1);
      a2 = fmaf(xs[k + 2], Uh[(k + 2) * 256 + t], a2);
      a3 = fmaf(xs[k + 3], Uh[(k + 3) * 256 + t], a3);
    }
    for (int k = 0; k < 256; k += 4) {
      a0 = fmaf(srs[k],     Wh[(k)     * 256 + t], a0);
      a1 = fmaf(srs[k + 1], Wh[(k + 1) * 256 + t], a1);
      a2 = fmaf(srs[k + 2], Wh[(k + 2) * 256 + t], a2);
      a3 = fmaf(srs[k + 3], Wh[(k + 3) * 256 + t], a3);
    }
    const float m = (a0 + a1) + (a2 + a3);
    const float h = tanhf(m);
    const int idx = b * 256 + t;
    const float z = zv[idx];
    ghv[idx]  = 1.f - h * h;
    pmhv[idx] = pv - h;
    muOut[idx] = z * pv + (1.f - z) * h;
    float s = srs[t] * srs[t];
#pragma unroll
    for (int off = 32; off; off >>= 1) s += __shfl_down(s, off, 64);
    __syncthreads();
    if ((t & 63) == 0) red[t >> 6] = s;
    __syncthreads();
    if (t == 0) ssrA[b] = red[0] + red[1] + red[2] + red[3];
    return;
  }

  // ---- gate0 / gate1 (XCD-grouped decode; per-block work identical to R6) ----
  const int q = blk - 128;
  const int c = q & 7, role = (q >> 3) & 7, chunk = q >> 6;
  const int b = chunk * 8 + c;
  const int isR = role >> 2, nb = role & 3, col0 = nb * 64;
  const int wave = tid >> 6, lane = tid & 63, lhi = lane >> 4, l15 = lane & 15;
  const size_t bb = (size_t)b << 16;
  const unsigned short* p1 = packs + (size_t)(isR ? 2 : 0) * 65536;
  const unsigned short* p2 = packs + (size_t)(isR ? 3 : 1) * 65536;

  {  // epilogue vectors + in-kernel diag
    const int u = tid;
    const float sd = spA[b] + trSA[b], sx = sxA[b];
    if (isR) {
      ev0[u] = grv[b * 256 + u];
      evd[u] = sd * sprw[u] + sx * spru[u];
      ev2[u] = prev[b * 256 + u];
      ev3[u] = rv[b * 256 + u];
    } else {
      ev0[u] = gzv[b * 256 + u];
      evd[u] = sd * spzw[u] + sx * spzu[u];
    }
  }

  f4 acc[4][4];
#pragma unroll
  for (int i = 0; i < 4; ++i)
#pragma unroll
    for (int j = 0; j < 4; ++j) acc[i][j] = z4;

  // stage 1: T = S_b @ W[:,col0:+64)   (A from Sfrag, B from pack1)
  const unsigned short* Af = Sfrag + bb;
#pragma unroll
  for (int kt = 0; kt < 8; ++kt) {
    sh8 af[4], bfr[4];
#pragma unroll
    for (int rt = 0; rt < 4; ++rt)
      af[rt] = *reinterpret_cast<const sh8*>(
          Af + kt * 8192 + (wave * 4 + rt) * 512 + lane * 8);
#pragma unroll
    for (int ct = 0; ct < 4; ++ct)
      bfr[ct] = *reinterpret_cast<const sh8*>(
          p1 + ((size_t)(((nb * 8 + kt) * 4 + ct) * 64 + lane) << 3));
#pragma unroll
    for (int rt = 0; rt < 4; ++rt)
#pragma unroll
      for (int ct = 0; ct < 4; ++ct)
        acc[rt][ct] = mfma16(af[rt], bfr[ct], acc[rt][ct]);
  }

  // T^T (bf16) -> LDS
#pragma unroll
  for (int rt = 0; rt < 4; ++rt) {
    const int row0 = wave * 64 + rt * 16 + lhi * 4;
#pragma unroll
    for (int ct = 0; ct < 4; ++ct) {
      const int cc = ct * 16 + l15;
      us4 p4;
      p4[0] = f2bf(acc[rt][ct][0]); p4[1] = f2bf(acc[rt][ct][1]);
      p4[2] = f2bf(acc[rt][ct][2]); p4[3] = f2bf(acc[rt][ct][3]);
      *reinterpret_cast<us4*>(&Tt[cc][row0]) = p4;
    }
  }
  __syncthreads();

#pragma unroll
  for (int i = 0; i < 4; ++i)
#pragma unroll
    for (int j = 0; j < 4; ++j) acc[i][j] = z4;

  // stage 2: Y = W^T @ T   (A from pack2, B from Tt)
#pragma unroll
  for (int jt = 0; jt < 8; ++jt) {
    const int j8 = jt * 32 + lhi * 8;
    sh8 af[4], bfr[4];
#pragma unroll
    for (int rt = 0; rt < 4; ++rt)
      af[rt] = *reinterpret_cast<const sh8*>(
          p2 + ((size_t)(((wave * 4 + rt) * 8 + jt) * 64 + lane) << 3));
#pragma unroll
    for (int ct = 0; ct < 4; ++ct)
      bfr[ct] = *reinterpret_cast<const sh8*>(&Tt[ct * 16 + l15][j8]);
#pragma unroll
    for (int rt = 0; rt < 4; ++rt)
#pragma unroll
      for (int ct = 0; ct < 4; ++ct)
        acc[rt][ct] = mfma16(af[rt], bfr[ct], acc[rt][ct]);
  }

  // epilogue
  float trloc = 0.f;
#pragma unroll
  for (int rt = 0; rt < 4; ++rt) {
    const int i0 = wave * 64 + rt * 16 + lhi * 4;
#pragma unroll
    for (int ct = 0; ct < 4; ++ct) {
      const int j = col0 + ct * 16 + l15;
#pragma unroll
      for (int rr = 0; rr < 4; ++rr) {
        const int i = i0 + rr;
        const size_t idx = bb + ((size_t)i << 8) + j;
        float Y = acc[rt][ct][rr] + ((i == j) ? evd[i] : 0.f);
        if (!isR) {
          Szbf[idx] = f2bf(Y * ev0[i] * ev0[j]);
        } else {
          float Sr = Y * ev0[i] * ev0[j];
          float Sv = S[idx];
          float sgv = Sr * (Sv + ev2[i] * ev2[j]) + ev3[i] * ev3[j] * Sv;
          // fragment-ordered store for gate2's A operand
          size_t fo = bb + (size_t)((j >> 5) * 8192) + (size_t)((i >> 4) * 512)
                    + (size_t)((((j >> 3) & 3) * 16 + (i & 15)) * 8) + (j & 7);
          sgf[fo] = f2bf(sgv);
          if (i == j) trloc += sgv;
        }
      }
    }
  }

  if (isR) {  // deterministic trace partials
    if (wave == nb) {
#pragma unroll
      for (int off = 32; off; off >>= 1) trloc += __shfl_down(trloc, off, 64);
      if (lane == 0) trsgP[b * 4 + nb] = trloc;
    }
  }
}

// ---------------------------------------------------------------------------
// K3 gateh: Sigma_out.  XCD-grouped: c=blk&7, nb=(blk>>3)&3, chunk=blk>>5,
// b=chunk*8+c.  Bijective (16*4*8=512).  Per-block work identical to R6.
// ---------------------------------------------------------------------------
__global__ __launch_bounds__(256) void gateh_kernel(
    const float* __restrict__ S,
    const unsigned short* __restrict__ sgf,
    const unsigned short* __restrict__ packs,
    const unsigned short* __restrict__ Szb,
    const float* __restrict__ ghv, const float* __restrict__ zv,
    const float* __restrict__ pmhv,
    const float* __restrict__ sphw, const float* __restrict__ sphu,
    const float* __restrict__ sxA, const float* __restrict__ ssrA,
    const float* __restrict__ trsgIn,
    float* __restrict__ fOut)
{
  __shared__ unsigned short Tt[64][264];
  __shared__ float ev0[256], evd[256], ev2[256], ev3[256];

  const int blk = blockIdx.x, tid = threadIdx.x;
  const int wave = tid >> 6, lane = tid & 63, lhi = lane >> 4, l15 = lane & 15;
  const int c = blk & 7, nb = (blk >> 3) & 3, chunk = blk >> 5;
  const int b = chunk * 8 + c, col0 = nb * 64;
  const size_t bb = (size_t)b << 16;
  const f4 z4 = {0.f, 0.f, 0.f, 0.f};
  const unsigned short* p1 = packs + (size_t)4 * 65536;
  const unsigned short* p2 = packs + (size_t)5 * 65536;

  {
    const int u = tid;
    float trsg = trsgIn[b * 4] + trsgIn[b * 4 + 1]
               + trsgIn[b * 4 + 2] + trsgIn[b * 4 + 3];
    ev0[u] = ghv[b * 256 + u];
    evd[u] = (ssrA[b] + trsg) * sphw[u] + sxA[b] * sphu[u];
    ev2[u] = zv[b * 256 + u];
    ev3[u] = pmhv[b * 256 + u];
  }

  f4 acc[4][4];
#pragma unroll
  for (int i = 0; i < 4; ++i)
#pragma unroll
    for (int j = 0; j < 4; ++j) acc[i][j] = z4;

  const unsigned short* Af = sgf + bb;
#pragma unroll
  for (int kt = 0; kt < 8; ++kt) {
    sh8 af[4], bfr[4];
#pragma unroll
    for (int rt = 0; rt < 4; ++rt)
      af[rt] = *reinterpret_cast<const sh8*>(
          Af + kt * 8192 + (wave * 4 + rt) * 512 + lane * 8);
#pragma unroll
    for (int ct = 0; ct < 4; ++ct)
      bfr[ct] = *reinterpret_cast<const sh8*>(
          p1 + ((size_t)(((nb * 8 + kt) * 4 + ct) * 64 + lane) << 3));
#pragma unroll
    for (int rt = 0; rt < 4; ++rt)
#pragma unroll
      for (int ct = 0; ct < 4; ++ct)
        acc[rt][ct] = mfma16(af[rt], bfr[ct], acc[rt][ct]);
  }

#pragma unroll
  for (int rt = 0; rt < 4; ++rt) {
    const int row0 = wave * 64 + rt * 16 + lhi * 4;
#pragma unroll
    for (int ct = 0; ct < 4; ++ct) {
      const int cc = ct * 16 + l15;
      us4 p4;
      p4[0] = f2bf(acc[rt][ct][0]); p4[1] = f2bf(acc[rt][ct][1]);
      p4[2] = f2bf(acc[rt][ct][2]); p4[3] = f2bf(acc[rt][ct][3]);
      *reinterpret_cast<us4*>(&Tt[cc][row0]) = p4;
    }
  }
  __syncthreads();

#pragma unroll
  for (int i = 0; i < 4; ++i)
#pragma unroll
    for (int j = 0; j < 4; ++j) acc[i][j] = z4;

#pragma unroll
  for (int jt = 0; jt < 8; ++jt) {
    const int j8 = jt * 32 + lhi * 8;
    sh8 af[4], bfr[4];
#pragma unroll
    for (int rt = 0; rt < 4; ++rt)
      af[rt] = *reinterpret_cast<const sh8*>(
          p2 + ((size_t)(((wave * 4 + rt) * 8 + jt) * 64 + lane) << 3));
#pragma unroll
    for (int ct = 0; ct < 4; ++ct)
      bfr[ct] = *reinterpret_cast<const sh8*>(&Tt[ct * 16 + l15][j8]);
#pragma unroll
    for (int rt = 0; rt < 4; ++rt)
#pragma unroll
      for (int ct = 0; ct < 4; ++ct)
        acc[rt][ct] = mfma16(af[rt], bfr[ct], acc[rt][ct]);
  }

#pragma unroll
  for (int rt = 0; rt < 4; ++rt) {
    const int i0 = wave * 64 + rt * 16 + lhi * 4;
#pragma unroll
    for (int ct = 0; ct < 4; ++ct) {
      const int j = col0 + ct * 16 + l15;
#pragma unroll
      for (int rr = 0; rr < 4; ++rr) {
        const int i = i0 + rr;
        const size_t idx = bb + ((size_t)i << 8) + j;
        float Sh = (acc[rt][ct][rr] + ((i == j) ? evd[i] : 0.f)) * ev0[i] * ev0[j];
        float Sv = S[idx];
        float Szv = bf2f(Szb[idx]);
        fOut[idx] = Szv * (Sv + Sh + ev3[i] * ev3[j])
                  + Sv * ev2[i] * ev2[j]
                  + Sh * (1.f - ev2[i]) * (1.f - ev2[j]);
      }
    }
  }
}

// ---------------------------------------------------------------------------
extern "C" void kernel_launch(void* const* d_in, const int* in_sizes, int n_in,
                              void* d_out, int out_size, void* d_ws, size_t ws_size,
                              hipStream_t stream)
{
  const float* xin  = (const float*)d_in[0];
  const float* prev = (const float*)d_in[1];
  const float* S    = (const float*)d_in[2];
  const float* Uz = (const float*)d_in[3];  const float* uzs = (const float*)d_in[4];
  const float* Wz = (const float*)d_in[5];  const float* wzs = (const float*)d_in[6];
  const float* Ur = (const float*)d_in[7];  const float* urs = (const float*)d_in[8];
  const float* Wr = (const float*)d_in[9];  const float* wrs = (const float*)d_in[10];
  const float* Uh = (const float*)d_in[11]; const float* uhs = (const float*)d_in[12];
  const float* Wh = (const float*)d_in[13]; const float* whs = (const float*)d_in[14];

  float* muOut  = (float*)d_out;
  float* SigOut = muOut + 128 * 256;

  char* p = (char*)d_ws;
  auto take = [&](size_t bytes) { void* q = (void*)p; p += bytes; return q; };
  unsigned short* Sfrag = (unsigned short*)take(16777216);  // S, frag order
  unsigned short* sgf   = (unsigned short*)take(16777216);  // sigma_g, frag order
  unsigned short* Szbf  = (unsigned short*)take(16777216);  // Sigma_z, linear
  unsigned short* packs = (unsigned short*)take(786432);    // 6 x 128KB
  float* zv   = (float*)take(131072);
  float* rv   = (float*)take(131072);
  float* gzv  = (float*)take(131072);
  float* grv  = (float*)take(131072);
  float* ghv  = (float*)take(131072);
  float* pmhv = (float*)take(131072);
  float* spzw = (float*)take(1024);
  float* spzu = (float*)take(1024);
  float* sprw = (float*)take(1024);
  float* spru = (float*)take(1024);
  float* sphw = (float*)take(1024);
  float* sphu = (float*)take(1024);
  float* sxA  = (float*)take(512);
  float* spA  = (float*)take(512);
  float* trSA = (float*)take(512);
  float* ssrA = (float*)take(512);
  float* trsgP = (float*)take(2048);
  (void)in_sizes; (void)n_in; (void)out_size; (void)ws_size;

  prep_kernel<<<2481, 256, 0, stream>>>(
      xin, prev, S, Uz, Wz, uzs, wzs, Ur, Wr, urs, wrs, Uh, Wh, uhs, whs,
      Sfrag, packs, spzw, spzu, sprw, spru, sphw, sphu,
      sxA, spA, trSA, zv, rv, gzv, grv);

  fuse_kernel<<<1152, 256, 0, stream>>>(
      xin, prev, S, Uh, Wh, zv, rv, gzv, grv, packs, Sfrag,
      spzw, spzu, sprw, spru, sxA, spA, trSA,
      Szbf, sgf, trsgP, ghv, pmhv, muOut, ssrA);

  gateh_kernel<<<512, 256, 0, stream>>>(
      S, sgf, packs, Szbf, ghv, zv, pmhv, sphw, sphu,
      sxA, ssrA, trsgP, SigOut);
}

// Round 9
// 90.685 us; speedup vs baseline: 2.7339x; 1.2033x over previous
//
#include <hip/hip_runtime.h>
#include <math.h>

// densityPropGRUCell on MI355X (gfx950).  B=128, U=D=256.
// R9 = R8 + ONE change: fuse's gate0/gate1 blocks merged (one block computes
// BOTH Sigma_z and sigma_g for a (batch, 64-col) tile).  z and r share the
// A operand (Sfrag_b): A-frags loaded once, two independent MFMA chains give
// 2x ILP per wave (fuse was latency-bound: MfmaUtil 9.8%, occ 15%).
// Arithmetic bit-identical to R8.  prep/gateh verbatim from R8.

typedef __attribute__((ext_vector_type(8))) short sh8;           // 8 x bf16
typedef __attribute__((ext_vector_type(4))) float f4;
typedef __attribute__((ext_vector_type(4))) unsigned short us4;  // 4 x bf16

__device__ __forceinline__ unsigned short f2bf(float f) {  // software RNE
  unsigned int u = __float_as_uint(f);
  u = (u + 0x7fffu + ((u >> 16) & 1u)) >> 16;
  return (unsigned short)u;
}
__device__ __forceinline__ float bf2f(unsigned short u) {
  return __uint_as_float(((unsigned int)u) << 16);
}
__device__ __forceinline__ f4 mfma16(sh8 a, sh8 b, f4 c) {
  return __builtin_amdgcn_mfma_f32_16x16x32_bf16(a, b, c, 0, 0, 0);
}

// Fragment chunk layout: chunk (b, kt, R): lane l, elem e holds
// M[b][R*16 + (l&15)][kt*32 + (l>>4)*8 + e]; short offset = b<<16 | kt*8192
// | R*512 | lane*8.

// ---------------------------------------------------------------------------
// K1 prep (R8 verbatim).
// ---------------------------------------------------------------------------
__global__ __launch_bounds__(256) void prep_kernel(
    const float* __restrict__ xin, const float* __restrict__ prev,
    const float* __restrict__ S,
    const float* __restrict__ Uz, const float* __restrict__ Wz,
    const float* __restrict__ uzs, const float* __restrict__ wzs,
    const float* __restrict__ Ur, const float* __restrict__ Wr,
    const float* __restrict__ urs, const float* __restrict__ wrs,
    const float* __restrict__ Uh, const float* __restrict__ Wh,
    const float* __restrict__ uhs, const float* __restrict__ whs,
    unsigned short* __restrict__ Sfrag, unsigned short* __restrict__ packs,
    float* __restrict__ spzw, float* __restrict__ spzu,
    float* __restrict__ sprw, float* __restrict__ spru,
    float* __restrict__ sphw, float* __restrict__ sphu,
    float* __restrict__ sxA, float* __restrict__ spA, float* __restrict__ trSA,
    float* __restrict__ zv, float* __restrict__ rv,
    float* __restrict__ gzv, float* __restrict__ grv)
{
  const int blk = blockIdx.x, t = threadIdx.x;
  __shared__ float Srows[16][260];
  __shared__ float xs[256], ps[256];

  if (blk < 2048) {  // ---- S -> Sfrag ----
    const int b = blk >> 4, R = blk & 15;
    const float* Sb = S + ((size_t)b << 16) + (size_t)(R * 16) * 256;
#pragma unroll
    for (int i = 0; i < 4; ++i) {
      int e = t + i * 256;
      int row = e >> 6, c4 = e & 63;
      f4 v = reinterpret_cast<const f4*>(Sb)[e];
      *reinterpret_cast<f4*>(&Srows[row][c4 * 4]) = v;
    }
    __syncthreads();
    unsigned short* outb = Sfrag + ((size_t)b << 16) + R * 512;
#pragma unroll
    for (int qi = 0; qi < 2; ++qi) {
      int q = t + qi * 256;
      int kt = q >> 6, lane = q & 63;
      int l15 = lane & 15, c0 = kt * 32 + (lane >> 4) * 8;
      union { unsigned short u[8]; uint4 v; } pk;
#pragma unroll
      for (int e = 0; e < 8; ++e) pk.u[e] = f2bf(Srows[l15][c0 + e]);
      *reinterpret_cast<uint4*>(outb + kt * 8192 + lane * 8) = pk.v;
    }
    return;
  }

  if (blk < 2096) {  // ---- pack builder (R2-proven) ----
    int gid = (blk - 2048) * 256 + t;
#pragma unroll
    for (int q2 = 0; q2 < 4; ++q2) {
      int cid = gid * 4 + q2;
      int p = cid >> 13, c = cid & 8191;
      const float* W = (p >> 1) == 0 ? Wz : ((p >> 1) == 1 ? Wr : Wh);
      int lane = c & 63, l15 = lane & 15, lhi = lane >> 4;
      int n, k8;
      if ((p & 1) == 0) {                 // pack1 (stage-1 B)
        int nb = (c >> 11) & 3, kt = (c >> 8) & 7, ct = (c >> 6) & 3;
        n = nb * 64 + ct * 16 + l15; k8 = kt * 32 + lhi * 8;
      } else {                            // pack2 (stage-2 A)
        int wv = (c >> 11) & 3, rt = (c >> 9) & 3, jt = (c >> 6) & 7;
        n = wv * 64 + rt * 16 + l15; k8 = jt * 32 + lhi * 8;
      }
      union { unsigned short u[8]; uint4 v; } pk;
#pragma unroll
      for (int e = 0; e < 8; ++e) pk.u[e] = f2bf(W[(k8 + e) * 256 + n]);
      *reinterpret_cast<uint4*>(packs + (size_t)p * 65536 + (size_t)c * 8) = pk.v;
    }
    return;
  }

  if (blk < 2224) {  // ---- per-batch reductions ----
    const int b = blk - 2096;
    __shared__ float red[12];
    float x = xin[b * 256 + t];
    float p = prev[b * 256 + t];
    float d = S[(size_t)b * 65536 + (size_t)t * 257];
    float a0 = x * x, a1 = p * p, a2 = d;
#pragma unroll
    for (int off = 32; off; off >>= 1) {
      a0 += __shfl_down(a0, off, 64);
      a1 += __shfl_down(a1, off, 64);
      a2 += __shfl_down(a2, off, 64);
    }
    if ((t & 63) == 0) {
      int w = t >> 6;
      red[w] = a0; red[4 + w] = a1; red[8 + w] = a2;
    }
    __syncthreads();
    if (t == 0) {
      sxA[b] = red[0] + red[1] + red[2] + red[3];
      spA[b] = red[4] + red[5] + red[6] + red[7];
      trSA[b] = red[8] + red[9] + red[10] + red[11];
    }
    return;
  }

  if (blk == 2224) {  // ---- softplus ----
    spzw[t] = log1pf(expf(wzs[t])); spzu[t] = log1pf(expf(uzs[t]));
    sprw[t] = log1pf(expf(wrs[t])); spru[t] = log1pf(expf(urs[t]));
    sphw[t] = log1pf(expf(whs[t])); sphu[t] = log1pf(expf(uhs[t]));
    return;
  }

  // ---- mean1 (R8 verbatim) ----
  const int q = blk - 2225, g = q >> 7, b = q & 127;
  xs[t] = xin[b * 256 + t];
  ps[t] = prev[b * 256 + t];
  __syncthreads();
  const float* U = g ? Ur : Uz;
  const float* W = g ? Wr : Wz;
  float a0 = 0.f, a1 = 0.f, a2 = 0.f, a3 = 0.f;
  for (int k = 0; k < 256; k += 4) {
    a0 = fmaf(xs[k],     U[(k)     * 256 + t], a0);
    a1 = fmaf(xs[k + 1], U[(k + 1) * 256 + t], a1);
    a2 = fmaf(xs[k + 2], U[(k + 2) * 256 + t], a2);
    a3 = fmaf(xs[k + 3], U[(k + 3) * 256 + t], a3);
  }
  for (int k = 0; k < 256; k += 4) {
    a0 = fmaf(ps[k],     W[(k)     * 256 + t], a0);
    a1 = fmaf(ps[k + 1], W[(k + 1) * 256 + t], a1);
    a2 = fmaf(ps[k + 2], W[(k + 2) * 256 + t], a2);
    a3 = fmaf(ps[k + 3], W[(k + 3) * 256 + t], a3);
  }
  const float m = (a0 + a1) + (a2 + a3);
  const float zz = 1.f / (1.f + expf(-m));
  const int idx = b * 256 + t;
  if (g == 0) { zv[idx] = zz; gzv[idx] = zz * (1.f - zz); }
  else        { rv[idx] = zz; grv[idx] = zz * (1.f - zz); }
}

// ---------------------------------------------------------------------------
// K2 fuse.
//  [0,128)   : mean2 (R8 verbatim)
//  [128,640) : MERGED gate0+gate1 per (b, nb).  XCD-grouped: q=blk-128,
//              c=q&7, nb=(q>>3)&3, chunk=q>>5, b=chunk*8+c (16*4*8=512).
// ---------------------------------------------------------------------------
__global__ __launch_bounds__(256, 2) void fuse_kernel(
    const float* __restrict__ xin, const float* __restrict__ prev,
    const float* __restrict__ S,
    const float* __restrict__ Uh, const float* __restrict__ Wh,
    const float* __restrict__ zv, const float* __restrict__ rv,
    const float* __restrict__ gzv, const float* __restrict__ grv,
    const unsigned short* __restrict__ packs,
    const unsigned short* __restrict__ Sfrag,
    const float* __restrict__ spzw, const float* __restrict__ spzu,
    const float* __restrict__ sprw, const float* __restrict__ spru,
    const float* __restrict__ sxA, const float* __restrict__ spA,
    const float* __restrict__ trSA,
    unsigned short* __restrict__ Szbf, unsigned short* __restrict__ sgf,
    float* __restrict__ trsgP,
    float* __restrict__ ghv, float* __restrict__ pmhv,
    float* __restrict__ muOut, float* __restrict__ ssrA)
{
  __shared__ unsigned short Ttz[64][264];
  __shared__ unsigned short Ttr[64][264];
  __shared__ float ev0z[256], evdz[256], ev0r[256], evdr[256];
  __shared__ float ev2[256], ev3[256];

  const int blk = blockIdx.x, tid = threadIdx.x;
  const f4 z4 = {0.f, 0.f, 0.f, 0.f};

  if (blk < 128) {  // ---- mean2 (R8 verbatim; scratch in Ttz) ----
    float* xs  = (float*)&Ttz[0][0];
    float* ps  = xs + 256;
    float* srs = ps + 256;
    float* red = srs + 256;
    const int b = blk, t = tid;
    xs[t] = xin[b * 256 + t];
    float pv = prev[b * 256 + t];
    ps[t] = pv;
    srs[t] = pv * rv[b * 256 + t];
    __syncthreads();
    float a0 = 0.f, a1 = 0.f, a2 = 0.f, a3 = 0.f;
    for (int k = 0; k < 256; k += 4) {
      a0 = fmaf(xs[k],     Uh[(k)     * 256 + t], a0);
      a1 = fmaf(xs[k + 1], Uh[(k + 1) * 256 + t], a1);
      a2 = fmaf(xs[k + 2], Uh[(k + 2) * 256 + t], a2);
      a3 = fmaf(xs[k + 3], Uh[(k + 3) * 256 + t], a3);
    }
    for (int k = 0; k < 256; k += 4) {
      a0 = fmaf(srs[k],     Wh[(k)     * 256 + t], a0);
      a1 = fmaf(srs[k + 1], Wh[(k + 1) * 256 + t], a1);
      a2 = fmaf(srs[k + 2], Wh[(k + 2) * 256 + t], a2);
      a3 = fmaf(srs[k + 3], Wh[(k + 3) * 256 + t], a3);
    }
    const float m = (a0 + a1) + (a2 + a3);
    const float h = tanhf(m);
    const int idx = b * 256 + t;
    const float z = zv[idx];
    ghv[idx]  = 1.f - h * h;
    pmhv[idx] = pv - h;
    muOut[idx] = z * pv + (1.f - z) * h;
    float s = srs[t] * srs[t];
#pragma unroll
    for (int off = 32; off; off >>= 1) s += __shfl_down(s, off, 64);
    __syncthreads();
    if ((t & 63) == 0) red[t >> 6] = s;
    __syncthreads();
    if (t == 0) ssrA[b] = red[0] + red[1] + red[2] + red[3];
    return;
  }

  // ---- merged gate0+gate1 ----
  const int q = blk - 128;
  const int c = q & 7, nb = (q >> 3) & 3, chunk = q >> 5;
  const int b = chunk * 8 + c;
  const int col0 = nb * 64;
  const int wave = tid >> 6, lane = tid & 63, lhi = lane >> 4, l15 = lane & 15;
  const size_t bb = (size_t)b << 16;
  const unsigned short* p1z = packs;
  const unsigned short* p2z = packs + (size_t)1 * 65536;
  const unsigned short* p1r = packs + (size_t)2 * 65536;
  const unsigned short* p2r = packs + (size_t)3 * 65536;

  {  // epilogue vectors + in-kernel diag (both gates)
    const int u = tid;
    const float sd = spA[b] + trSA[b], sx = sxA[b];
    ev0z[u] = gzv[b * 256 + u];
    evdz[u] = sd * spzw[u] + sx * spzu[u];
    ev0r[u] = grv[b * 256 + u];
    evdr[u] = sd * sprw[u] + sx * spru[u];
    ev2[u]  = prev[b * 256 + u];
    ev3[u]  = rv[b * 256 + u];
  }

  f4 az[4][4], ar[4][4];
#pragma unroll
  for (int i = 0; i < 4; ++i)
#pragma unroll
    for (int j = 0; j < 4; ++j) { az[i][j] = z4; ar[i][j] = z4; }

  // stage 1: Tz = S_b @ Wz[:,cols), Tr = S_b @ Wr[:,cols) -- shared A
  const unsigned short* Af = Sfrag + bb;
#pragma unroll
  for (int kt = 0; kt < 8; ++kt) {
    sh8 af[4], bz[4], br[4];
#pragma unroll
    for (int rt = 0; rt < 4; ++rt)
      af[rt] = *reinterpret_cast<const sh8*>(
          Af + kt * 8192 + (wave * 4 + rt) * 512 + lane * 8);
#pragma unroll
    for (int ct = 0; ct < 4; ++ct) {
      const size_t po = (size_t)(((nb * 8 + kt) * 4 + ct) * 64 + lane) << 3;
      bz[ct] = *reinterpret_cast<const sh8*>(p1z + po);
      br[ct] = *reinterpret_cast<const sh8*>(p1r + po);
    }
#pragma unroll
    for (int rt = 0; rt < 4; ++rt)
#pragma unroll
      for (int ct = 0; ct < 4; ++ct) {
        az[rt][ct] = mfma16(af[rt], bz[ct], az[rt][ct]);
        ar[rt][ct] = mfma16(af[rt], br[ct], ar[rt][ct]);
      }
  }

  // T^T (bf16) -> LDS, both gates
#pragma unroll
  for (int rt = 0; rt < 4; ++rt) {
    const int row0 = wave * 64 + rt * 16 + lhi * 4;
#pragma unroll
    for (int ct = 0; ct < 4; ++ct) {
      const int cc = ct * 16 + l15;
      us4 pz, pr;
      pz[0] = f2bf(az[rt][ct][0]); pz[1] = f2bf(az[rt][ct][1]);
      pz[2] = f2bf(az[rt][ct][2]); pz[3] = f2bf(az[rt][ct][3]);
      pr[0] = f2bf(ar[rt][ct][0]); pr[1] = f2bf(ar[rt][ct][1]);
      pr[2] = f2bf(ar[rt][ct][2]); pr[3] = f2bf(ar[rt][ct][3]);
      *reinterpret_cast<us4*>(&Ttz[cc][row0]) = pz;
      *reinterpret_cast<us4*>(&Ttr[cc][row0]) = pr;
    }
  }
  __syncthreads();

#pragma unroll
  for (int i = 0; i < 4; ++i)
#pragma unroll
    for (int j = 0; j < 4; ++j) { az[i][j] = z4; ar[i][j] = z4; }

  // stage 2: Yz = Wz^T Tz, Yr = Wr^T Tr
#pragma unroll
  for (int jt = 0; jt < 8; ++jt) {
    const int j8 = jt * 32 + lhi * 8;
    sh8 a2z[4], a2r[4], bz[4], br[4];
#pragma unroll
    for (int rt = 0; rt < 4; ++rt) {
      const size_t po = (size_t)(((wave * 4 + rt) * 8 + jt) * 64 + lane) << 3;
      a2z[rt] = *reinterpret_cast<const sh8*>(p2z + po);
      a2r[rt] = *reinterpret_cast<const sh8*>(p2r + po);
    }
#pragma unroll
    for (int ct = 0; ct < 4; ++ct) {
      bz[ct] = *reinterpret_cast<const sh8*>(&Ttz[ct * 16 + l15][j8]);
      br[ct] = *reinterpret_cast<const sh8*>(&Ttr[ct * 16 + l15][j8]);
    }
#pragma unroll
    for (int rt = 0; rt < 4; ++rt)
#pragma unroll
      for (int ct = 0; ct < 4; ++ct) {
        az[rt][ct] = mfma16(a2z[rt], bz[ct], az[rt][ct]);
        ar[rt][ct] = mfma16(a2r[rt], br[ct], ar[rt][ct]);
      }
  }

  // epilogue: both gates (R8 arithmetic verbatim)
  float trloc = 0.f;
#pragma unroll
  for (int rt = 0; rt < 4; ++rt) {
    const int i0 = wave * 64 + rt * 16 + lhi * 4;
#pragma unroll
    for (int ct = 0; ct < 4; ++ct) {
      const int j = col0 + ct * 16 + l15;
#pragma unroll
      for (int rr = 0; rr < 4; ++rr) {
        const int i = i0 + rr;
        const size_t idx = bb + ((size_t)i << 8) + j;
        // gate z
        float Yz = az[rt][ct][rr] + ((i == j) ? evdz[i] : 0.f);
        Szbf[idx] = f2bf(Yz * ev0z[i] * ev0z[j]);
        // gate r
        float Yr = ar[rt][ct][rr] + ((i == j) ? evdr[i] : 0.f);
        float Sr = Yr * ev0r[i] * ev0r[j];
        float Sv = S[idx];
        float sgv = Sr * (Sv + ev2[i] * ev2[j]) + ev3[i] * ev3[j] * Sv;
        size_t fo = bb + (size_t)((j >> 5) * 8192) + (size_t)((i >> 4) * 512)
                  + (size_t)((((j >> 3) & 3) * 16 + (i & 15)) * 8) + (j & 7);
        sgf[fo] = f2bf(sgv);
        if (i == j) trloc += sgv;
      }
    }
  }

  // deterministic trace partials (same wave==nb scheme)
  if (wave == nb) {
#pragma unroll
    for (int off = 32; off; off >>= 1) trloc += __shfl_down(trloc, off, 64);
    if (lane == 0) trsgP[b * 4 + nb] = trloc;
  }
}

// ---------------------------------------------------------------------------
// K3 gateh (R8 verbatim).
// ---------------------------------------------------------------------------
__global__ __launch_bounds__(256) void gateh_kernel(
    const float* __restrict__ S,
    const unsigned short* __restrict__ sgf,
    const unsigned short* __restrict__ packs,
    const unsigned short* __restrict__ Szb,
    const float* __restrict__ ghv, const float* __restrict__ zv,
    const float* __restrict__ pmhv,
    const float* __restrict__ sphw, const float* __restrict__ sphu,
    const float* __restrict__ sxA, const float* __restrict__ ssrA,
    const float* __restrict__ trsgIn,
    float* __restrict__ fOut)
{
  __shared__ unsigned short Tt[64][264];
  __shared__ float ev0[256], evd[256], ev2[256], ev3[256];

  const int blk = blockIdx.x, tid = threadIdx.x;
  const int wave = tid >> 6, lane = tid & 63, lhi = lane >> 4, l15 = lane & 15;
  const int c = blk & 7, nb = (blk >> 3) & 3, chunk = blk >> 5;
  const int b = chunk * 8 + c, col0 = nb * 64;
  const size_t bb = (size_t)b << 16;
  const f4 z4 = {0.f, 0.f, 0.f, 0.f};
  const unsigned short* p1 = packs + (size_t)4 * 65536;
  const unsigned short* p2 = packs + (size_t)5 * 65536;

  {
    const int u = tid;
    float trsg = trsgIn[b * 4] + trsgIn[b * 4 + 1]
               + trsgIn[b * 4 + 2] + trsgIn[b * 4 + 3];
    ev0[u] = ghv[b * 256 + u];
    evd[u] = (ssrA[b] + trsg) * sphw[u] + sxA[b] * sphu[u];
    ev2[u] = zv[b * 256 + u];
    ev3[u] = pmhv[b * 256 + u];
  }

  f4 acc[4][4];
#pragma unroll
  for (int i = 0; i < 4; ++i)
#pragma unroll
    for (int j = 0; j < 4; ++j) acc[i][j] = z4;

  const unsigned short* Af = sgf + bb;
#pragma unroll
  for (int kt = 0; kt < 8; ++kt) {
    sh8 af[4], bfr[4];
#pragma unroll
    for (int rt = 0; rt < 4; ++rt)
      af[rt] = *reinterpret_cast<const sh8*>(
          Af + kt * 8192 + (wave * 4 + rt) * 512 + lane * 8);
#pragma unroll
    for (int ct = 0; ct < 4; ++ct)
      bfr[ct] = *reinterpret_cast<const sh8*>(
          p1 + ((size_t)(((nb * 8 + kt) * 4 + ct) * 64 + lane) << 3));
#pragma unroll
    for (int rt = 0; rt < 4; ++rt)
#pragma unroll
      for (int ct = 0; ct < 4; ++ct)
        acc[rt][ct] = mfma16(af[rt], bfr[ct], acc[rt][ct]);
  }

#pragma unroll
  for (int rt = 0; rt < 4; ++rt) {
    const int row0 = wave * 64 + rt * 16 + lhi * 4;
#pragma unroll
    for (int ct = 0; ct < 4; ++ct) {
      const int cc = ct * 16 + l15;
      us4 p4;
      p4[0] = f2bf(acc[rt][ct][0]); p4[1] = f2bf(acc[rt][ct][1]);
      p4[2] = f2bf(acc[rt][ct][2]); p4[3] = f2bf(acc[rt][ct][3]);
      *reinterpret_cast<us4*>(&Tt[cc][row0]) = p4;
    }
  }
  __syncthreads();

#pragma unroll
  for (int i = 0; i < 4; ++i)
#pragma unroll
    for (int j = 0; j < 4; ++j) acc[i][j] = z4;

#pragma unroll
  for (int jt = 0; jt < 8; ++jt) {
    const int j8 = jt * 32 + lhi * 8;
    sh8 af[4], bfr[4];
#pragma unroll
    for (int rt = 0; rt < 4; ++rt)
      af[rt] = *reinterpret_cast<const sh8*>(
          p2 + ((size_t)(((wave * 4 + rt) * 8 + jt) * 64 + lane) << 3));
#pragma unroll
    for (int ct = 0; ct < 4; ++ct)
      bfr[ct] = *reinterpret_cast<const sh8*>(&Tt[ct * 16 + l15][j8]);
#pragma unroll
    for (int rt = 0; rt < 4; ++rt)
#pragma unroll
      for (int ct = 0; ct < 4; ++ct)
        acc[rt][ct] = mfma16(af[rt], bfr[ct], acc[rt][ct]);
  }

#pragma unroll
  for (int rt = 0; rt < 4; ++rt) {
    const int i0 = wave * 64 + rt * 16 + lhi * 4;
#pragma unroll
    for (int ct = 0; ct < 4; ++ct) {
      const int j = col0 + ct * 16 + l15;
#pragma unroll
      for (int rr = 0; rr < 4; ++rr) {
        const int i = i0 + rr;
        const size_t idx = bb + ((size_t)i << 8) + j;
        float Sh = (acc[rt][ct][rr] + ((i == j) ? evd[i] : 0.f)) * ev0[i] * ev0[j];
        float Sv = S[idx];
        float Szv = bf2f(Szb[idx]);
        fOut[idx] = Szv * (Sv + Sh + ev3[i] * ev3[j])
                  + Sv * ev2[i] * ev2[j]
                  + Sh * (1.f - ev2[i]) * (1.f - ev2[j]);
      }
    }
  }
}

// ---------------------------------------------------------------------------
extern "C" void kernel_launch(void* const* d_in, const int* in_sizes, int n_in,
                              void* d_out, int out_size, void* d_ws, size_t ws_size,
                              hipStream_t stream)
{
  const float* xin  = (const float*)d_in[0];
  const float* prev = (const float*)d_in[1];
  const float* S    = (const float*)d_in[2];
  const float* Uz = (const float*)d_in[3];  const float* uzs = (const float*)d_in[4];
  const float* Wz = (const float*)d_in[5];  const float* wzs = (const float*)d_in[6];
  const float* Ur = (const float*)d_in[7];  const float* urs = (const float*)d_in[8];
  const float* Wr = (const float*)d_in[9];  const float* wrs = (const float*)d_in[10];
  const float* Uh = (const float*)d_in[11]; const float* uhs = (const float*)d_in[12];
  const float* Wh = (const float*)d_in[13]; const float* whs = (const float*)d_in[14];

  float* muOut  = (float*)d_out;
  float* SigOut = muOut + 128 * 256;

  char* p = (char*)d_ws;
  auto take = [&](size_t bytes) { void* q = (void*)p; p += bytes; return q; };
  unsigned short* Sfrag = (unsigned short*)take(16777216);  // S, frag order
  unsigned short* sgf   = (unsigned short*)take(16777216);  // sigma_g, frag order
  unsigned short* Szbf  = (unsigned short*)take(16777216);  // Sigma_z, linear
  unsigned short* packs = (unsigned short*)take(786432);    // 6 x 128KB
  float* zv   = (float*)take(131072);
  float* rv   = (float*)take(131072);
  float* gzv  = (float*)take(131072);
  float* grv  = (float*)take(131072);
  float* ghv  = (float*)take(131072);
  float* pmhv = (float*)take(131072);
  float* spzw = (float*)take(1024);
  float* spzu = (float*)take(1024);
  float* sprw = (float*)take(1024);
  float* spru = (float*)take(1024);
  float* sphw = (float*)take(1024);
  float* sphu = (float*)take(1024);
  float* sxA  = (float*)take(512);
  float* spA  = (float*)take(512);
  float* trSA = (float*)take(512);
  float* ssrA = (float*)take(512);
  float* trsgP = (float*)take(2048);
  (void)in_sizes; (void)n_in; (void)out_size; (void)ws_size;

  prep_kernel<<<2481, 256, 0, stream>>>(
      xin, prev, S, Uz, Wz, uzs, wzs, Ur, Wr, urs, wrs, Uh, Wh, uhs, whs,
      Sfrag, packs, spzw, spzu, sprw, spru, sphw, sphu,
      sxA, spA, trSA, zv, rv, gzv, grv);

  fuse_kernel<<<640, 256, 0, stream>>>(
      xin, prev, S, Uh, Wh, zv, rv, gzv, grv, packs, Sfrag,
      spzw, spzu, sprw, spru, sxA, spA, trSA,
      Szbf, sgf, trsgP, ghv, pmhv, muOut, ssrA);

  gateh_kernel<<<512, 256, 0, stream>>>(
      S, sgf, packs, Szbf, ghv, zv, pmhv, sphw, sphu,
      sxA, ssrA, trsgP, SigOut);
}